// Round 15
// baseline (286.456 us; speedup 1.0000x reference)
//
#include <hip/hip_runtime.h>
#include <hip/hip_bf16.h>

#define BB 4
#define CPG 48
#define HH 128
#define WW2 128
#define PP 16384
#define DIM 384
#define DIM3 1152

typedef unsigned short u16;
typedef __attribute__((ext_vector_type(8))) short bf16x8;
typedef __attribute__((ext_vector_type(4))) float f32x4;

__device__ __forceinline__ float bf2f(u16 u) {
    return __uint_as_float(((unsigned int)u) << 16);
}
__device__ __forceinline__ u16 f2bf(float f) {
    unsigned int u = __float_as_uint(f);
    unsigned int r = (u + 0x7fffu + ((u >> 16) & 1u)) >> 16;
    return (u16)r;
}

// LDS swizzle: rows are 128B; XOR the 16B-slot index with (row&7) to spread banks
__device__ __forceinline__ int swz(int row, int kb) {
    return row * 128 + (kb ^ ((row & 7) << 4));
}

// async global->LDS, 16B per lane; LDS dest = wave-uniform base + lane*16
__device__ __forceinline__ void gld_lds16(const u16* g, char* l) {
    __builtin_amdgcn_global_load_lds(
        (const __attribute__((address_space(1))) void*)g,
        (__attribute__((address_space(3))) void*)l, 16, 0, 0);
}

// ---------------- convert w_qkv fp32 -> bf16
__global__ __launch_bounds__(256) void k_wcvt(const float* __restrict__ w,
                                              u16* __restrict__ wbf)
{
    const int i4 = (blockIdx.x * 256 + threadIdx.x) * 4;
    float4 v = *reinterpret_cast<const float4*>(w + i4);
    ushort4 s;
    s.x = f2bf(v.x); s.y = f2bf(v.y); s.z = f2bf(v.z); s.w = f2bf(v.w);
    *reinterpret_cast<ushort4*>(wbf + i4) = s;
}

// ---------------- transpose x [b][k=384][p] fp32 -> Xt [b][p][k=384] bf16
__global__ __launch_bounds__(256) void k_tr_x(const float* __restrict__ x,
                                              u16* __restrict__ xt)
{
    const int b = blockIdx.z;
    const int k0 = blockIdx.y * 64;
    const int p0 = blockIdx.x * 64;
    const int t = threadIdx.x;
    __shared__ u16 T[64][68];

    const int kl = t >> 4;          // 0..15
    const int pl = (t & 15) * 4;    // 0..60
#pragma unroll
    for (int ks = 0; ks < 4; ++ks) {
        const int k = ks * 16 + kl;
        float4 v = *reinterpret_cast<const float4*>(&x[((size_t)b * DIM + k0 + k) * PP + p0 + pl]);
        ushort4 s;
        s.x = f2bf(v.x); s.y = f2bf(v.y); s.z = f2bf(v.z); s.w = f2bf(v.w);
        *reinterpret_cast<ushort4*>(&T[k][pl]) = s;
    }
    __syncthreads();
    const int pr = t >> 2;          // 0..63
    const int kg = (t & 3) * 16;    // 0,16,32,48
    __align__(16) u16 tmp[16];
#pragma unroll
    for (int j = 0; j < 16; ++j) tmp[j] = T[kg + j][pr];
    u16* dst = xt + ((size_t)b * PP + p0 + pr) * DIM + k0 + kg;
    *reinterpret_cast<uint4*>(dst)     = *reinterpret_cast<uint4*>(tmp);
    *reinterpret_cast<uint4*>(dst + 8) = *reinterpret_cast<uint4*>(tmp + 8);
}

// ---------------- MFMA GEMM: C[b][co][p] = sum_k A[(b)][co][k] * Bt[b][p][k]
// MODE 0: += bias, write bf16 ybf.  MODE 1: += bias + xres, write fp32 fout.
// Staging via global_load_lds(16B) with pre-swizzled per-lane GLOBAL source.
template<int MODE>
__global__ __launch_bounds__(256) void k_gemm(const u16* __restrict__ A, int aStride,
                                              const u16* __restrict__ Bt,
                                              const float* __restrict__ bias,
                                              u16* __restrict__ ybf,
                                              const float* __restrict__ xres,
                                              float* __restrict__ fout,
                                              int nyTiles)
{
    const int bid = blockIdx.x;
    const int xcd = bid & 7;
    const int r1  = bid >> 3;
    const int px  = xcd * 16 + (r1 & 15);   // p-tile 0..127
    const int r2  = r1 >> 4;
    const int b   = r2 / nyTiles;           // batch
    const int yt  = r2 - b * nyTiles;       // co-tile
    const int co0 = yt * 128;
    const int p0  = px * 128;

    const int t   = threadIdx.x;
    const int l   = t & 63;
    const int wid = t >> 6;
    const int wr  = wid >> 1;      // 0..1 -> row half
    const int wc  = wid & 1;       // 0..1 -> col half
    const int lr  = l & 15;
    const int lg  = l >> 4;        // 0..3

    __shared__ __align__(16) char lds[32768];
    char* AsB = lds;               // [128 rows][64 k] bf16, swizzled content
    char* BsB = lds + 16384;

    f32x4 acc[4][4];
#pragma unroll
    for (int m = 0; m < 4; ++m)
#pragma unroll
        for (int n = 0; n < 4; ++n) acc[m][n] = (f32x4){0.f, 0.f, 0.f, 0.f};

    const u16* Ab  = A  + (size_t)b * aStride;
    const u16* Btb = Bt + (size_t)b * PP * DIM;

    // per-lane source mapping for gld_lds16 (8 rows / wave-issue)
    const int lrow8 = l >> 3;                 // 0..7 within the 8-row group
    const int sl    = l & 7;                  // 16B slot 0..7 within 128B row

    for (int k0 = 0; k0 < DIM; k0 += 64) {
        if (k0) __syncthreads();   // prev iter's LDS reads complete
#pragma unroll
        for (int i = 0; i < 4; ++i) {
            const int rbase = wid * 32 + i * 8;
            const int row   = rbase + lrow8;
            const int elem  = (sl * 8) ^ ((row & 7) << 3);   // inverse swizzle
            gld_lds16(Ab  + (size_t)(co0 + row) * DIM + k0 + elem, AsB + rbase * 128);
            gld_lds16(Btb + (size_t)(p0  + row) * DIM + k0 + elem, BsB + rbase * 128);
        }
        __syncthreads();           // drains vmcnt(0) then barrier -> tiles ready

#pragma unroll
        for (int kk = 0; kk < 64; kk += 32) {
            const int kbyte = kk * 2 + lg * 16;
            bf16x8 av[4], bv[4];
#pragma unroll
            for (int m = 0; m < 4; ++m) {
                const int row = wr * 64 + m * 16 + lr;
                av[m] = *reinterpret_cast<const bf16x8*>(AsB + swz(row, kbyte));
            }
#pragma unroll
            for (int n = 0; n < 4; ++n) {
                const int row = wc * 64 + n * 16 + lr;
                bv[n] = *reinterpret_cast<const bf16x8*>(BsB + swz(row, kbyte));
            }
#pragma unroll
            for (int m = 0; m < 4; ++m)
#pragma unroll
                for (int n = 0; n < 4; ++n)
                    acc[m][n] = __builtin_amdgcn_mfma_f32_16x16x32_bf16(
                        av[m], bv[n], acc[m][n], 0, 0, 0);
        }
    }

    // bias per (m, r): row = wr*64 + m*16 + lg*4 + r
    float bias_r[4][4];
#pragma unroll
    for (int m = 0; m < 4; ++m)
#pragma unroll
        for (int r = 0; r < 4; ++r)
            bias_r[m][r] = bias[co0 + wr * 64 + m * 16 + lg * 4 + r];

    if (MODE == 0) {
        __syncthreads();
        u16* Cs = reinterpret_cast<u16*>(lds);
#pragma unroll
        for (int m = 0; m < 4; ++m)
#pragma unroll
            for (int n = 0; n < 4; ++n)
#pragma unroll
                for (int r = 0; r < 4; ++r) {
                    const int row = wr * 64 + m * 16 + lg * 4 + r;
                    const int col = wc * 64 + n * 16 + lr;
                    Cs[row * 128 + col] = f2bf(acc[m][n][r] + bias_r[m][r]);
                }
        __syncthreads();
        // coalesced store: 16 lanes cover one 256B row segment
        const int rr = t >> 4;          // 0..15
        const int cs = (t & 15) * 8;    // u16 col
#pragma unroll
        for (int j = 0; j < 8; ++j) {
            const int row = j * 16 + rr;
            *reinterpret_cast<uint4*>(&ybf[((size_t)b * DIM3 + co0 + row) * PP + p0 + cs]) =
                *reinterpret_cast<const uint4*>(&Cs[row * 128 + cs]);
        }
    } else {
        // fp32 epilogue via LDS in two 64-row half-passes
        float* Cf = reinterpret_cast<float*>(lds);
#pragma unroll
        for (int h = 0; h < 2; ++h) {
            __syncthreads();
            if (wr == h) {
#pragma unroll
                for (int m = 0; m < 4; ++m)
#pragma unroll
                    for (int n = 0; n < 4; ++n)
#pragma unroll
                        for (int r = 0; r < 4; ++r) {
                            const int lrow = m * 16 + lg * 4 + r;
                            const int col = wc * 64 + n * 16 + lr;
                            Cf[lrow * 128 + col] = acc[m][n][r] + bias_r[m][r];
                        }
            }
            __syncthreads();
            const int rr = t >> 5;          // 0..7
            const int cc = (t & 31) * 4;    // fp32 col
#pragma unroll
            for (int j = 0; j < 8; ++j) {
                const int lrow = j * 8 + rr;
                const int grow = h * 64 + lrow;
                const size_t idx = ((size_t)b * DIM + co0 + grow) * PP + p0 + cc;
                float4 xr = *reinterpret_cast<const float4*>(&xres[idx]);
                float4 cv = *reinterpret_cast<const float4*>(&Cf[lrow * 128 + cc]);
                cv.x += xr.x; cv.y += xr.y; cv.z += xr.z; cv.w += xr.w;
                *reinterpret_cast<float4*>(&fout[idx]) = cv;
            }
        }
    }
}

// ---------------- fused dw(v) + transpose -> vt[b][p][c]  (y2v eliminated)
// Block = (64-px half-row, 64 v-channels, b). Thread = 1 channel x 16 px.
__global__ __launch_bounds__(256) void k_dwtr(const u16* __restrict__ y1,
                                              const float* __restrict__ wdw,
                                              const float* __restrict__ bdw,
                                              u16* __restrict__ vt)
{
    const int b  = blockIdx.z;
    const int cg = blockIdx.y;              // channel group 0..5
    const int p0 = blockIdx.x * 64;         // pixel base
    const int rr = p0 >> 7;                 // image row
    const int hc = (p0 >> 6) & 1;           // half-row 0|1
    const int t  = (int)threadIdx.x;
    const int ch = t >> 2;                  // 0..63
    const int q  = t & 3;                   // px quarter 0..3
    const int cb = hc * 64 + q * 16;        // col base in image row

    const int gch = 2 * DIM + cg * 64 + ch;
    const u16* img = y1 + ((size_t)b * DIM3 + gch) * PP;

    float w9[9];
#pragma unroll
    for (int i = 0; i < 9; ++i) w9[i] = wdw[gch * 9 + i];
    const float bv = bdw[gch];

    __shared__ __align__(16) u16 T[64][72];

    float R[3][18];
#pragma unroll
    for (int dr = 0; dr < 3; ++dr) {
        const int r_ = rr + dr - 1;
        const bool inrow = (r_ >= 0 && r_ < HH);
        if (inrow) {
            union { uint4 v; u16 u[8]; } c0_, c1_;
            c0_.v = *reinterpret_cast<const uint4*>(img + r_ * WW2 + cb);
            c1_.v = *reinterpret_cast<const uint4*>(img + r_ * WW2 + cb + 8);
#pragma unroll
            for (int j = 0; j < 8; ++j) {
                R[dr][1 + j] = bf2f(c0_.u[j]);
                R[dr][9 + j] = bf2f(c1_.u[j]);
            }
        } else {
#pragma unroll
            for (int j = 0; j < 16; ++j) R[dr][1 + j] = 0.f;
        }
        const float lf = __shfl(R[dr][16], t - 1);
        const float rt = __shfl(R[dr][1],  t + 1);
        // left halo: interior via shuffle; 63/64 boundary via scalar; image edge 0
        if (q > 0)           R[dr][0] = lf;
        else if (hc == 1)    R[dr][0] = inrow ? bf2f(img[r_ * WW2 + 63]) : 0.f;
        else                 R[dr][0] = 0.f;
        if (q < 3)           R[dr][17] = rt;
        else if (hc == 0)    R[dr][17] = inrow ? bf2f(img[r_ * WW2 + 64]) : 0.f;
        else                 R[dr][17] = 0.f;
    }

#pragma unroll
    for (int j = 0; j < 16; ++j) {
        float a = bv;
        a = fmaf(w9[0], R[0][j],     a);
        a = fmaf(w9[1], R[0][j + 1], a);
        a = fmaf(w9[2], R[0][j + 2], a);
        a = fmaf(w9[3], R[1][j],     a);
        a = fmaf(w9[4], R[1][j + 1], a);
        a = fmaf(w9[5], R[1][j + 2], a);
        a = fmaf(w9[6], R[2][j],     a);
        a = fmaf(w9[7], R[2][j + 1], a);
        a = fmaf(w9[8], R[2][j + 2], a);
        T[q * 16 + j][ch] = f2bf(a);
    }
    __syncthreads();

    const int pl = t >> 2;          // local px 0..63
    const int cc = (t & 3) * 16;    // 16-ch chunk
    u16* dst = vt + ((size_t)b * PP + p0 + pl) * DIM + cg * 64 + cc;
    *reinterpret_cast<uint4*>(dst)     = *reinterpret_cast<const uint4*>(&T[pl][cc]);
    *reinterpret_cast<uint4*>(dst + 8) = *reinterpret_cast<const uint4*>(&T[pl][cc + 8]);
}

// halo load for k_dwqk: 8 px strip on one row, shuffles for column halo
#define LOADROW2(arr, gr_)                                                     \
    {                                                                          \
        const int r_ = (gr_);                                                  \
        if (r_ >= 0 && r_ < HH) {                                              \
            union { uint4 v; u16 u[8]; } cc_;                                  \
            cc_.v = *reinterpret_cast<const uint4*>(img + r_ * WW2 + sp);      \
            arr[1] = bf2f(cc_.u[0]); arr[2] = bf2f(cc_.u[1]);                  \
            arr[3] = bf2f(cc_.u[2]); arr[4] = bf2f(cc_.u[3]);                  \
            arr[5] = bf2f(cc_.u[4]); arr[6] = bf2f(cc_.u[5]);                  \
            arr[7] = bf2f(cc_.u[6]); arr[8] = bf2f(cc_.u[7]);                  \
        } else {                                                               \
            arr[1] = 0.f; arr[2] = 0.f; arr[3] = 0.f; arr[4] = 0.f;            \
            arr[5] = 0.f; arr[6] = 0.f; arr[7] = 0.f; arr[8] = 0.f;            \
        }                                                                      \
        float lf_ = __shfl(arr[8], t - 1);                                     \
        float rt_ = __shfl(arr[1], t + 1);                                     \
        arr[0] = (s > 0)  ? lf_ : 0.f;                                         \
        arr[9] = (s < 15) ? rt_ : 0.f;                                         \
    }

// ---------------- fused dw(q,k) + MFMA self-Gram. Block = (c, band of 8 rows, b).
__global__ __launch_bounds__(256) void k_dwqk(const u16* __restrict__ y1,
                                              const float* __restrict__ wdw,
                                              const float* __restrict__ bdw,
                                              float* __restrict__ partial)
{
    const int c    = blockIdx.x;   // 0..47
    const int band = blockIdx.y;   // 0..15
    const int b    = blockIdx.z;   // 0..3
    const int t    = (int)threadIdx.x;
    const int h    = t >> 7;       // 0=q set, 1=k set (wave-uniform)
    const int r    = (t >> 4) & 7; // row within band
    const int s    = t & 15;       // 8-px strip
    const int sp   = s * 8;
    const int r0   = band * 8;

    __shared__ __align__(16) u16 G[16][1032];    // 16 x (1024 + 8 pad) bf16 = 33KB
    __shared__ __align__(16) float red[4][256];  // 4KB

#pragma unroll
    for (int n = 0; n < 8; ++n) {
        const int gch = h * DIM + n * CPG + c;
        const u16* img = y1 + ((size_t)b * DIM3 + gch) * PP;
        float w9[9];
#pragma unroll
        for (int i = 0; i < 9; ++i) w9[i] = wdw[gch * 9 + i];
        const float bv = bdw[gch];

        float A[10], B[10], C[10];
        LOADROW2(A, r0 + r - 1);
        LOADROW2(B, r0 + r);
        LOADROW2(C, r0 + r + 1);

        union { uint4 v; u16 u[8]; } og;
#pragma unroll
        for (int j = 0; j < 8; ++j) {
            float a = bv;
            a = fmaf(w9[0], A[j],     a);
            a = fmaf(w9[1], A[j + 1], a);
            a = fmaf(w9[2], A[j + 2], a);
            a = fmaf(w9[3], B[j],     a);
            a = fmaf(w9[4], B[j + 1], a);
            a = fmaf(w9[5], B[j + 2], a);
            a = fmaf(w9[6], C[j],     a);
            a = fmaf(w9[7], C[j + 1], a);
            a = fmaf(w9[8], C[j + 2], a);
            og.u[j] = f2bf(a);
        }
        *reinterpret_cast<uint4*>(&G[h * 8 + n][r * 128 + sp]) = og.v;
    }
    __syncthreads();

    // Gram: wave w covers K range [w*256, w*256+256)
    const int l = t & 63, w = t >> 6;
    const int grow = l & 15;
    const int koc  = (l >> 4) * 8;
    f32x4 acc = (f32x4){0.f, 0.f, 0.f, 0.f};
#pragma unroll
    for (int q8 = 0; q8 < 8; ++q8) {
        const int koff = w * 256 + q8 * 32 + koc;
        bf16x8 g = *reinterpret_cast<const bf16x8*>(&G[grow][koff]);
        acc = __builtin_amdgcn_mfma_f32_16x16x32_bf16(g, g, acc, 0, 0, 0);
    }
    // C/D layout: col = lane&15, row = (lane>>4)*4 + reg  ->  S[row][col]
#pragma unroll
    for (int rg = 0; rg < 4; ++rg)
        red[w][((l >> 4) * 4 + rg) * 16 + (l & 15)] = acc[rg];
    __syncthreads();

    const float sum = red[0][t] + red[1][t] + red[2][t] + red[3][t];
    partial[((size_t)((b * 48 + c) * 16 + band)) * 256 + t] = sum;
}

// ---------------- reduce partials (768 rows x 256 / b), normalize, softmax -> attn
__global__ __launch_bounds__(256) void k_attn(const float* __restrict__ partial,
                                              const float* __restrict__ temp,
                                              float* __restrict__ attn)
{
    const int b = blockIdx.x;
    const int t = threadIdx.x;
    __shared__ float S[256];
    __shared__ float sc[8][8];
    float s = 0.f;
    for (int i = 0; i < 768; ++i)
        s += partial[((size_t)b * 768 + i) * 256 + t];
    S[t] = s;
    __syncthreads();
    if (t < 64) {
        const int n = t >> 3, m = t & 7;
        const float qn = fmaxf(sqrtf(S[n * 16 + n]), 1e-12f);
        const float km = fmaxf(sqrtf(S[(8 + m) * 16 + 8 + m]), 1e-12f);
        sc[n][m] = S[n * 16 + 8 + m] / (qn * km) * temp[0];
    }
    __syncthreads();
    if (t < 8) {
        float mx = -3.0e38f;
#pragma unroll
        for (int m = 0; m < 8; ++m) mx = fmaxf(mx, sc[t][m]);
        float e[8], ssum = 0.f;
#pragma unroll
        for (int m = 0; m < 8; ++m) { e[m] = expf(sc[t][m] - mx); ssum += e[m]; }
        const float inv = 1.f / ssum;
#pragma unroll
        for (int m = 0; m < 8; ++m) attn[(b * 8 + t) * 8 + m] = e[m] * inv;
    }
}

// ---------------- Weff[b][co][m*48+c] = sum_n wproj[co][n*48+c]*attn[n][m]  (bf16 out)
__global__ __launch_bounds__(128) void k_weff(const float* __restrict__ attn,
                                              const float* __restrict__ wproj,
                                              u16* __restrict__ weff)
{
    const int b  = blockIdx.y;
    const int co = blockIdx.x;
    const int t  = threadIdx.x;
    __shared__ float a[64];
    if (t < 64) a[t] = attn[b * 64 + t];
    __syncthreads();
    const float* wrow = wproj + (size_t)co * DIM;
    u16* wout = weff + ((size_t)b * DIM + co) * DIM;
    for (int i = t; i < DIM; i += 128) {
        const int m = i / CPG;
        const int c = i - m * CPG;
        float s = 0.f;
#pragma unroll
        for (int n = 0; n < 8; ++n) s += wrow[n * CPG + c] * a[n * 8 + m];
        wout[i] = f2bf(s);
    }
}

extern "C" void kernel_launch(void* const* d_in, const int* in_sizes, int n_in,
                              void* d_out, int out_size, void* d_ws, size_t ws_size,
                              hipStream_t stream)
{
    const float* x      = (const float*)d_in[0];
    const float* temp   = (const float*)d_in[1];
    const float* w_qkv  = (const float*)d_in[2];
    const float* b_qkv  = (const float*)d_in[3];
    const float* w_dw   = (const float*)d_in[4];
    const float* b_dw   = (const float*)d_in[5];
    const float* w_proj = (const float*)d_in[6];
    const float* b_proj = (const float*)d_in[7];
    float* out = (float*)d_out;

    char* ws = (char*)d_ws;
    const size_t SZ_QKV = (size_t)BB * DIM3 * PP * sizeof(u16);  // 150,994,944
    const size_t SZ_XT  = (size_t)BB * PP * DIM * sizeof(u16);   //  50,331,648

    // region 0: [0, SZ_QKV) -- y1 (gemm0 out; read by k_dwtr/k_dwqk)
    u16* y1 = (u16*)ws;

    // region 1: [SZ_QKV, 2*SZ_QKV)
    u16* xt  = (u16*)(ws + SZ_QKV);               // pre-gemm0 only
    u16* wbf = (u16*)(ws + SZ_QKV + SZ_XT);       // pre-gemm0 only
    // after gemm0 (xt/wbf dead):
    float* partial = (float*)(ws + SZ_QKV);              // 3,145,728 B
    float* attn    = (float*)(ws + SZ_QKV + 3145728);    // 1,024 B
    u16*   weffb   = (u16*)(ws + SZ_QKV + 3211264);      // 1,179,648 B (ends ~4.4MB)
    u16*   vt      = (u16*)(ws + SZ_QKV + 8388608);      // 50.3MB (ends ~58.7MB)

    k_wcvt<<<dim3(DIM3 * DIM / 1024), 256, 0, stream>>>(w_qkv, wbf);
    k_tr_x<<<dim3(PP / 64, DIM / 64, BB), 256, 0, stream>>>(x, xt);
    k_gemm<0><<<dim3(128 * 9 * BB), 256, 0, stream>>>(
        wbf, 0, xt, b_qkv, y1, nullptr, nullptr, 9);
    k_dwtr<<<dim3(PP / 64, DIM / 64, BB), 256, 0, stream>>>(y1, w_dw, b_dw, vt);
    k_dwqk<<<dim3(48, 16, BB), 256, 0, stream>>>(y1, w_dw, b_dw, partial);
    k_attn<<<dim3(BB), 256, 0, stream>>>(partial, temp, attn);
    k_weff<<<dim3(DIM, BB), 128, 0, stream>>>(attn, w_proj, weffb);
    k_gemm<1><<<dim3(128 * 3 * BB), 256, 0, stream>>>(
        weffb, DIM * DIM, vt, b_proj, nullptr, x, out, 3);
}

// Round 16
// 266.354 us; speedup vs baseline: 1.0755x; 1.0755x over previous
//
#include <hip/hip_runtime.h>
#include <hip/hip_bf16.h>

#define BB 4
#define CPG 48
#define HH 128
#define WW2 128
#define PP 16384
#define DIM 384
#define DIM3 1152

typedef unsigned short u16;
typedef __attribute__((ext_vector_type(8))) short bf16x8;
typedef __attribute__((ext_vector_type(4))) float f32x4;

__device__ __forceinline__ float bf2f(u16 u) {
    return __uint_as_float(((unsigned int)u) << 16);
}
__device__ __forceinline__ u16 f2bf(float f) {
    unsigned int u = __float_as_uint(f);
    unsigned int r = (u + 0x7fffu + ((u >> 16) & 1u)) >> 16;
    return (u16)r;
}

// LDS swizzle: rows are 128B; XOR the 16B-slot index with (row&7) to spread banks
__device__ __forceinline__ int swz(int row, int kb) {
    return row * 128 + (kb ^ ((row & 7) << 4));
}

// async global->LDS, 16B per lane; LDS dest = wave-uniform base + lane*16
__device__ __forceinline__ void gld_lds16(const u16* g, char* l) {
    __builtin_amdgcn_global_load_lds(
        (const __attribute__((address_space(1))) void*)g,
        (__attribute__((address_space(3))) void*)l, 16, 0, 0);
}

// ---------------- convert w_qkv fp32 -> bf16
__global__ __launch_bounds__(256) void k_wcvt(const float* __restrict__ w,
                                              u16* __restrict__ wbf)
{
    const int i4 = (blockIdx.x * 256 + threadIdx.x) * 4;
    float4 v = *reinterpret_cast<const float4*>(w + i4);
    ushort4 s;
    s.x = f2bf(v.x); s.y = f2bf(v.y); s.z = f2bf(v.z); s.w = f2bf(v.w);
    *reinterpret_cast<ushort4*>(wbf + i4) = s;
}

// ---------------- transpose x [b][k=384][p] fp32 -> Xt [b][p][k=384] bf16
__global__ __launch_bounds__(256) void k_tr_x(const float* __restrict__ x,
                                              u16* __restrict__ xt)
{
    const int b = blockIdx.z;
    const int k0 = blockIdx.y * 64;
    const int p0 = blockIdx.x * 64;
    const int t = threadIdx.x;
    __shared__ u16 T[64][68];

    const int kl = t >> 4;          // 0..15
    const int pl = (t & 15) * 4;    // 0..60
#pragma unroll
    for (int ks = 0; ks < 4; ++ks) {
        const int k = ks * 16 + kl;
        float4 v = *reinterpret_cast<const float4*>(&x[((size_t)b * DIM + k0 + k) * PP + p0 + pl]);
        ushort4 s;
        s.x = f2bf(v.x); s.y = f2bf(v.y); s.z = f2bf(v.z); s.w = f2bf(v.w);
        *reinterpret_cast<ushort4*>(&T[k][pl]) = s;
    }
    __syncthreads();
    const int pr = t >> 2;          // 0..63
    const int kg = (t & 3) * 16;    // 0,16,32,48
    __align__(16) u16 tmp[16];
#pragma unroll
    for (int j = 0; j < 16; ++j) tmp[j] = T[kg + j][pr];
    u16* dst = xt + ((size_t)b * PP + p0 + pr) * DIM + k0 + kg;
    *reinterpret_cast<uint4*>(dst)     = *reinterpret_cast<uint4*>(tmp);
    *reinterpret_cast<uint4*>(dst + 8) = *reinterpret_cast<uint4*>(tmp + 8);
}

// ---------------- MFMA GEMM: C[b][co][p] = sum_k A[(b)][co][k] * Bt[b][p][k]
// MODE 0: += bias, write bf16 ybf.  MODE 1: += bias + xres, write fp32 fout.
// Staging via global_load_lds(16B) with pre-swizzled per-lane GLOBAL source.
template<int MODE>
__global__ __launch_bounds__(256) void k_gemm(const u16* __restrict__ A, int aStride,
                                              const u16* __restrict__ Bt,
                                              const float* __restrict__ bias,
                                              u16* __restrict__ ybf,
                                              const float* __restrict__ xres,
                                              float* __restrict__ fout,
                                              int nyTiles)
{
    const int bid = blockIdx.x;
    const int xcd = bid & 7;
    const int r1  = bid >> 3;
    const int px  = xcd * 16 + (r1 & 15);   // p-tile 0..127
    const int r2  = r1 >> 4;
    const int b   = r2 / nyTiles;           // batch
    const int yt  = r2 - b * nyTiles;       // co-tile
    const int co0 = yt * 128;
    const int p0  = px * 128;

    const int t   = threadIdx.x;
    const int l   = t & 63;
    const int wid = t >> 6;
    const int wr  = wid >> 1;      // 0..1 -> row half
    const int wc  = wid & 1;       // 0..1 -> col half
    const int lr  = l & 15;
    const int lg  = l >> 4;        // 0..3

    __shared__ __align__(16) char lds[32768];
    char* AsB = lds;               // [128 rows][64 k] bf16, swizzled content
    char* BsB = lds + 16384;

    f32x4 acc[4][4];
#pragma unroll
    for (int m = 0; m < 4; ++m)
#pragma unroll
        for (int n = 0; n < 4; ++n) acc[m][n] = (f32x4){0.f, 0.f, 0.f, 0.f};

    const u16* Ab  = A  + (size_t)b * aStride;
    const u16* Btb = Bt + (size_t)b * PP * DIM;

    // per-lane source mapping for gld_lds16 (8 rows / wave-issue)
    const int lrow8 = l >> 3;                 // 0..7 within the 8-row group
    const int sl    = l & 7;                  // 16B slot 0..7 within 128B row

    for (int k0 = 0; k0 < DIM; k0 += 64) {
        if (k0) __syncthreads();   // prev iter's LDS reads complete
#pragma unroll
        for (int i = 0; i < 4; ++i) {
            const int rbase = wid * 32 + i * 8;
            const int row   = rbase + lrow8;
            const int elem  = (sl * 8) ^ ((row & 7) << 3);   // inverse swizzle
            gld_lds16(Ab  + (size_t)(co0 + row) * DIM + k0 + elem, AsB + rbase * 128);
            gld_lds16(Btb + (size_t)(p0  + row) * DIM + k0 + elem, BsB + rbase * 128);
        }
        __syncthreads();           // drains vmcnt(0) then barrier -> tiles ready

#pragma unroll
        for (int kk = 0; kk < 64; kk += 32) {
            const int kbyte = kk * 2 + lg * 16;
            bf16x8 av[4], bv[4];
#pragma unroll
            for (int m = 0; m < 4; ++m) {
                const int row = wr * 64 + m * 16 + lr;
                av[m] = *reinterpret_cast<const bf16x8*>(AsB + swz(row, kbyte));
            }
#pragma unroll
            for (int n = 0; n < 4; ++n) {
                const int row = wc * 64 + n * 16 + lr;
                bv[n] = *reinterpret_cast<const bf16x8*>(BsB + swz(row, kbyte));
            }
#pragma unroll
            for (int m = 0; m < 4; ++m)
#pragma unroll
                for (int n = 0; n < 4; ++n)
                    acc[m][n] = __builtin_amdgcn_mfma_f32_16x16x32_bf16(
                        av[m], bv[n], acc[m][n], 0, 0, 0);
        }
    }

    // bias per (m, r): row = wr*64 + m*16 + lg*4 + r
    float bias_r[4][4];
#pragma unroll
    for (int m = 0; m < 4; ++m)
#pragma unroll
        for (int r = 0; r < 4; ++r)
            bias_r[m][r] = bias[co0 + wr * 64 + m * 16 + lg * 4 + r];

    if (MODE == 0) {
        __syncthreads();
        u16* Cs = reinterpret_cast<u16*>(lds);
#pragma unroll
        for (int m = 0; m < 4; ++m)
#pragma unroll
            for (int n = 0; n < 4; ++n)
#pragma unroll
                for (int r = 0; r < 4; ++r) {
                    const int row = wr * 64 + m * 16 + lg * 4 + r;
                    const int col = wc * 64 + n * 16 + lr;
                    Cs[row * 128 + col] = f2bf(acc[m][n][r] + bias_r[m][r]);
                }
        __syncthreads();
        // coalesced store: 16 lanes cover one 256B row segment
        const int rr = t >> 4;          // 0..15
        const int cs = (t & 15) * 8;    // u16 col
#pragma unroll
        for (int j = 0; j < 8; ++j) {
            const int row = j * 16 + rr;
            *reinterpret_cast<uint4*>(&ybf[((size_t)b * DIM3 + co0 + row) * PP + p0 + cs]) =
                *reinterpret_cast<const uint4*>(&Cs[row * 128 + cs]);
        }
    } else {
        // fp32 epilogue via LDS in two 64-row half-passes
        float* Cf = reinterpret_cast<float*>(lds);
#pragma unroll
        for (int h = 0; h < 2; ++h) {
            __syncthreads();
            if (wr == h) {
#pragma unroll
                for (int m = 0; m < 4; ++m)
#pragma unroll
                    for (int n = 0; n < 4; ++n)
#pragma unroll
                        for (int r = 0; r < 4; ++r) {
                            const int lrow = m * 16 + lg * 4 + r;
                            const int col = wc * 64 + n * 16 + lr;
                            Cf[lrow * 128 + col] = acc[m][n][r] + bias_r[m][r];
                        }
            }
            __syncthreads();
            const int rr = t >> 5;          // 0..7
            const int cc = (t & 31) * 4;    // fp32 col
#pragma unroll
            for (int j = 0; j < 8; ++j) {
                const int lrow = j * 8 + rr;
                const int grow = h * 64 + lrow;
                const size_t idx = ((size_t)b * DIM + co0 + grow) * PP + p0 + cc;
                float4 xr = *reinterpret_cast<const float4*>(&xres[idx]);
                float4 cv = *reinterpret_cast<const float4*>(&Cf[lrow * 128 + cc]);
                cv.x += xr.x; cv.y += xr.y; cv.z += xr.z; cv.w += xr.w;
                *reinterpret_cast<float4*>(&fout[idx]) = cv;
            }
        }
    }
}

// ---------------- fused dw(v) + transpose -> vt[b][p][c], strip-mined v2
// Block = 4-row band x 128 cols x 32 channels. Threads 256 = 32ch x 8 strips(16px).
#define LOADROW3(arr, gr_)                                                     \
    {                                                                          \
        const int r_ = (gr_);                                                  \
        if (r_ >= 0 && r_ < HH) {                                              \
            union { uint4 v; u16 u[8]; } a0_, a1_;                             \
            a0_.v = *reinterpret_cast<const uint4*>(img + r_ * WW2 + c0);      \
            a1_.v = *reinterpret_cast<const uint4*>(img + r_ * WW2 + c0 + 8);  \
            arr[1] = bf2f(a0_.u[0]); arr[2] = bf2f(a0_.u[1]);                  \
            arr[3] = bf2f(a0_.u[2]); arr[4] = bf2f(a0_.u[3]);                  \
            arr[5] = bf2f(a0_.u[4]); arr[6] = bf2f(a0_.u[5]);                  \
            arr[7] = bf2f(a0_.u[6]); arr[8] = bf2f(a0_.u[7]);                  \
            arr[9]  = bf2f(a1_.u[0]); arr[10] = bf2f(a1_.u[1]);                \
            arr[11] = bf2f(a1_.u[2]); arr[12] = bf2f(a1_.u[3]);                \
            arr[13] = bf2f(a1_.u[4]); arr[14] = bf2f(a1_.u[5]);                \
            arr[15] = bf2f(a1_.u[6]); arr[16] = bf2f(a1_.u[7]);                \
        } else {                                                               \
            for (int z_ = 1; z_ <= 16; ++z_) arr[z_] = 0.f;                    \
        }                                                                      \
        float lf_ = __shfl(arr[16], t - 1);                                    \
        float rt_ = __shfl(arr[1],  t + 1);                                    \
        arr[0]  = (s > 0) ? lf_ : 0.f;                                         \
        arr[17] = (s < 7) ? rt_ : 0.f;                                         \
    }

__global__ __launch_bounds__(256) void k_dwtr(const u16* __restrict__ y1,
                                              const float* __restrict__ wdw,
                                              const float* __restrict__ bdw,
                                              u16* __restrict__ vt)
{
    const int band = blockIdx.x;   // 0..31 (4-row bands)
    const int chg  = blockIdx.y;   // 0..11 (32-ch groups)
    const int b    = blockIdx.z;
    const int t    = (int)threadIdx.x;
    const int ch   = t >> 3;       // 0..31
    const int s    = t & 7;        // 16-px strip
    const int c0   = s * 16;
    const int r0   = band * 4;

    const int gch = 2 * DIM + chg * 32 + ch;
    const u16* img = y1 + ((size_t)b * DIM3 + gch) * PP;

    float w9[9];
#pragma unroll
    for (int i = 0; i < 9; ++i) w9[i] = wdw[gch * 9 + i];
    const float bv = bdw[gch];

    // [ch][4*128 px + 8 pad]: row stride 1040B (16B-aligned, 4-bank ch skew)
    __shared__ __align__(16) u16 T[32][520];

    float A[18], B[18], C[18];
    LOADROW3(A, r0 - 1);
    LOADROW3(B, r0);

#pragma unroll
    for (int j = 0; j < 4; ++j) {
        LOADROW3(C, r0 + j + 1);
        union { uint4 v[2]; u16 u[16]; } og;
#pragma unroll
        for (int cidx = 0; cidx < 16; ++cidx) {
            float a = bv;
            a = fmaf(w9[0], A[cidx],     a);
            a = fmaf(w9[1], A[cidx + 1], a);
            a = fmaf(w9[2], A[cidx + 2], a);
            a = fmaf(w9[3], B[cidx],     a);
            a = fmaf(w9[4], B[cidx + 1], a);
            a = fmaf(w9[5], B[cidx + 2], a);
            a = fmaf(w9[6], C[cidx],     a);
            a = fmaf(w9[7], C[cidx + 1], a);
            a = fmaf(w9[8], C[cidx + 2], a);
            og.u[cidx] = f2bf(a);
        }
        *reinterpret_cast<uint4*>(&T[ch][j * 128 + c0])     = og.v[0];
        *reinterpret_cast<uint4*>(&T[ch][j * 128 + c0 + 8]) = og.v[1];
#pragma unroll
        for (int q = 0; q < 18; ++q) { A[q] = B[q]; B[q] = C[q]; }
    }
    __syncthreads();

    // transpose store: lane = px, gather 32 ch (conflict-free), 64B/px line
#pragma unroll
    for (int j = 0; j < 2; ++j) {
        const int px = j * 256 + t;           // 0..511
        union { uint4 v[4]; u16 u[32]; } ov;
#pragma unroll
        for (int c2 = 0; c2 < 32; ++c2) ov.u[c2] = T[c2][px];
        u16* dst = vt + ((size_t)b * PP + band * 512 + px) * DIM + chg * 32;
        *reinterpret_cast<uint4*>(dst)      = ov.v[0];
        *reinterpret_cast<uint4*>(dst + 8)  = ov.v[1];
        *reinterpret_cast<uint4*>(dst + 16) = ov.v[2];
        *reinterpret_cast<uint4*>(dst + 24) = ov.v[3];
    }
}

// halo load for k_dwqk: 8 px strip on one row, shuffles for column halo
#define LOADROW2(arr, gr_)                                                     \
    {                                                                          \
        const int r_ = (gr_);                                                  \
        if (r_ >= 0 && r_ < HH) {                                              \
            union { uint4 v; u16 u[8]; } cc_;                                  \
            cc_.v = *reinterpret_cast<const uint4*>(img + r_ * WW2 + sp);      \
            arr[1] = bf2f(cc_.u[0]); arr[2] = bf2f(cc_.u[1]);                  \
            arr[3] = bf2f(cc_.u[2]); arr[4] = bf2f(cc_.u[3]);                  \
            arr[5] = bf2f(cc_.u[4]); arr[6] = bf2f(cc_.u[5]);                  \
            arr[7] = bf2f(cc_.u[6]); arr[8] = bf2f(cc_.u[7]);                  \
        } else {                                                               \
            arr[1] = 0.f; arr[2] = 0.f; arr[3] = 0.f; arr[4] = 0.f;            \
            arr[5] = 0.f; arr[6] = 0.f; arr[7] = 0.f; arr[8] = 0.f;            \
        }                                                                      \
        float lf_ = __shfl(arr[8], t - 1);                                     \
        float rt_ = __shfl(arr[1], t + 1);                                     \
        arr[0] = (s > 0)  ? lf_ : 0.f;                                         \
        arr[9] = (s < 15) ? rt_ : 0.f;                                         \
    }

// ---------------- fused dw(q,k) + MFMA self-Gram. Block = (c, band of 8 rows, b).
__global__ __launch_bounds__(256) void k_dwqk(const u16* __restrict__ y1,
                                              const float* __restrict__ wdw,
                                              const float* __restrict__ bdw,
                                              float* __restrict__ partial)
{
    const int c    = blockIdx.x;   // 0..47
    const int band = blockIdx.y;   // 0..15
    const int b    = blockIdx.z;   // 0..3
    const int t    = (int)threadIdx.x;
    const int h    = t >> 7;       // 0=q set, 1=k set (wave-uniform)
    const int r    = (t >> 4) & 7; // row within band
    const int s    = t & 15;       // 8-px strip
    const int sp   = s * 8;
    const int r0   = band * 8;

    __shared__ __align__(16) u16 G[16][1032];    // 16 x (1024 + 8 pad) bf16 = 33KB
    __shared__ __align__(16) float red[4][256];  // 4KB

#pragma unroll
    for (int n = 0; n < 8; ++n) {
        const int gch = h * DIM + n * CPG + c;
        const u16* img = y1 + ((size_t)b * DIM3 + gch) * PP;
        float w9[9];
#pragma unroll
        for (int i = 0; i < 9; ++i) w9[i] = wdw[gch * 9 + i];
        const float bv = bdw[gch];

        float A[10], B[10], C[10];
        LOADROW2(A, r0 + r - 1);
        LOADROW2(B, r0 + r);
        LOADROW2(C, r0 + r + 1);

        union { uint4 v; u16 u[8]; } og;
#pragma unroll
        for (int j = 0; j < 8; ++j) {
            float a = bv;
            a = fmaf(w9[0], A[j],     a);
            a = fmaf(w9[1], A[j + 1], a);
            a = fmaf(w9[2], A[j + 2], a);
            a = fmaf(w9[3], B[j],     a);
            a = fmaf(w9[4], B[j + 1], a);
            a = fmaf(w9[5], B[j + 2], a);
            a = fmaf(w9[6], C[j],     a);
            a = fmaf(w9[7], C[j + 1], a);
            a = fmaf(w9[8], C[j + 2], a);
            og.u[j] = f2bf(a);
        }
        *reinterpret_cast<uint4*>(&G[h * 8 + n][r * 128 + sp]) = og.v;
    }
    __syncthreads();

    // Gram: wave w covers K range [w*256, w*256+256)
    const int l = t & 63, w = t >> 6;
    const int grow = l & 15;
    const int koc  = (l >> 4) * 8;
    f32x4 acc = (f32x4){0.f, 0.f, 0.f, 0.f};
#pragma unroll
    for (int q8 = 0; q8 < 8; ++q8) {
        const int koff = w * 256 + q8 * 32 + koc;
        bf16x8 g = *reinterpret_cast<const bf16x8*>(&G[grow][koff]);
        acc = __builtin_amdgcn_mfma_f32_16x16x32_bf16(g, g, acc, 0, 0, 0);
    }
    // C/D layout: col = lane&15, row = (lane>>4)*4 + reg  ->  S[row][col]
#pragma unroll
    for (int rg = 0; rg < 4; ++rg)
        red[w][((l >> 4) * 4 + rg) * 16 + (l & 15)] = acc[rg];
    __syncthreads();

    const float sum = red[0][t] + red[1][t] + red[2][t] + red[3][t];
    partial[((size_t)((b * 48 + c) * 16 + band)) * 256 + t] = sum;
}

// ---------------- reduce partials (768 rows x 256 / b), normalize, softmax -> attn
__global__ __launch_bounds__(256) void k_attn(const float* __restrict__ partial,
                                              const float* __restrict__ temp,
                                              float* __restrict__ attn)
{
    const int b = blockIdx.x;
    const int t = threadIdx.x;
    __shared__ float S[256];
    __shared__ float sc[8][8];
    float s = 0.f;
    for (int i = 0; i < 768; ++i)
        s += partial[((size_t)b * 768 + i) * 256 + t];
    S[t] = s;
    __syncthreads();
    if (t < 64) {
        const int n = t >> 3, m = t & 7;
        const float qn = fmaxf(sqrtf(S[n * 16 + n]), 1e-12f);
        const float km = fmaxf(sqrtf(S[(8 + m) * 16 + 8 + m]), 1e-12f);
        sc[n][m] = S[n * 16 + 8 + m] / (qn * km) * temp[0];
    }
    __syncthreads();
    if (t < 8) {
        float mx = -3.0e38f;
#pragma unroll
        for (int m = 0; m < 8; ++m) mx = fmaxf(mx, sc[t][m]);
        float e[8], ssum = 0.f;
#pragma unroll
        for (int m = 0; m < 8; ++m) { e[m] = expf(sc[t][m] - mx); ssum += e[m]; }
        const float inv = 1.f / ssum;
#pragma unroll
        for (int m = 0; m < 8; ++m) attn[(b * 8 + t) * 8 + m] = e[m] * inv;
    }
}

// ---------------- Weff[b][co][m*48+c] = sum_n wproj[co][n*48+c]*attn[n][m]  (bf16 out)
__global__ __launch_bounds__(128) void k_weff(const float* __restrict__ attn,
                                              const float* __restrict__ wproj,
                                              u16* __restrict__ weff)
{
    const int b  = blockIdx.y;
    const int co = blockIdx.x;
    const int t  = threadIdx.x;
    __shared__ float a[64];
    if (t < 64) a[t] = attn[b * 64 + t];
    __syncthreads();
    const float* wrow = wproj + (size_t)co * DIM;
    u16* wout = weff + ((size_t)b * DIM + co) * DIM;
    for (int i = t; i < DIM; i += 128) {
        const int m = i / CPG;
        const int c = i - m * CPG;
        float s = 0.f;
#pragma unroll
        for (int n = 0; n < 8; ++n) s += wrow[n * CPG + c] * a[n * 8 + m];
        wout[i] = f2bf(s);
    }
}

extern "C" void kernel_launch(void* const* d_in, const int* in_sizes, int n_in,
                              void* d_out, int out_size, void* d_ws, size_t ws_size,
                              hipStream_t stream)
{
    const float* x      = (const float*)d_in[0];
    const float* temp   = (const float*)d_in[1];
    const float* w_qkv  = (const float*)d_in[2];
    const float* b_qkv  = (const float*)d_in[3];
    const float* w_dw   = (const float*)d_in[4];
    const float* b_dw   = (const float*)d_in[5];
    const float* w_proj = (const float*)d_in[6];
    const float* b_proj = (const float*)d_in[7];
    float* out = (float*)d_out;

    char* ws = (char*)d_ws;
    const size_t SZ_QKV = (size_t)BB * DIM3 * PP * sizeof(u16);  // 150,994,944
    const size_t SZ_XT  = (size_t)BB * PP * DIM * sizeof(u16);   //  50,331,648

    // region 0: [0, SZ_QKV) -- y1 (gemm0 out; read by k_dwtr/k_dwqk)
    u16* y1 = (u16*)ws;

    // region 1: [SZ_QKV, 2*SZ_QKV)
    u16* xt  = (u16*)(ws + SZ_QKV);               // pre-gemm0 only
    u16* wbf = (u16*)(ws + SZ_QKV + SZ_XT);       // pre-gemm0 only
    // after gemm0 (xt/wbf dead):
    float* partial = (float*)(ws + SZ_QKV);              // 3,145,728 B
    float* attn    = (float*)(ws + SZ_QKV + 3145728);    // 1,024 B
    u16*   weffb   = (u16*)(ws + SZ_QKV + 3211264);      // 1,179,648 B (ends ~4.4MB)
    u16*   vt      = (u16*)(ws + SZ_QKV + 8388608);      // 50.3MB (ends ~58.7MB)

    k_wcvt<<<dim3(DIM3 * DIM / 1024), 256, 0, stream>>>(w_qkv, wbf);
    k_tr_x<<<dim3(PP / 64, DIM / 64, BB), 256, 0, stream>>>(x, xt);
    k_gemm<0><<<dim3(128 * 9 * BB), 256, 0, stream>>>(
        wbf, 0, xt, b_qkv, y1, nullptr, nullptr, 9);
    k_dwtr<<<dim3(32, 12, BB), 256, 0, stream>>>(y1, w_dw, b_dw, vt);
    k_dwqk<<<dim3(48, 16, BB), 256, 0, stream>>>(y1, w_dw, b_dw, partial);
    k_attn<<<dim3(BB), 256, 0, stream>>>(partial, temp, attn);
    k_weff<<<dim3(DIM, BB), 128, 0, stream>>>(attn, w_proj, weffb);
    k_gemm<1><<<dim3(128 * 3 * BB), 256, 0, stream>>>(
        weffb, DIM * DIM, vt, b_proj, nullptr, x, out, 3);
}

// Round 17
// 252.683 us; speedup vs baseline: 1.1337x; 1.0541x over previous
//
#include <hip/hip_runtime.h>
#include <hip/hip_bf16.h>

#define BB 4
#define CPG 48
#define HH 128
#define WW2 128
#define PP 16384
#define DIM 384
#define DIM3 1152

typedef unsigned short u16;
typedef __attribute__((ext_vector_type(8))) short bf16x8;
typedef __attribute__((ext_vector_type(4))) float f32x4;

__device__ __forceinline__ float bf2f(u16 u) {
    return __uint_as_float(((unsigned int)u) << 16);
}
__device__ __forceinline__ u16 f2bf(float f) {
    unsigned int u = __float_as_uint(f);
    unsigned int r = (u + 0x7fffu + ((u >> 16) & 1u)) >> 16;
    return (u16)r;
}

// LDS swizzle: rows are 128B; XOR the 16B-slot index with (row&7) to spread banks
__device__ __forceinline__ int swz(int row, int kb) {
    return row * 128 + (kb ^ ((row & 7) << 4));
}

// async global->LDS, 16B per lane; LDS dest = wave-uniform base + lane*16
__device__ __forceinline__ void gld_lds16(const u16* g, char* l) {
    __builtin_amdgcn_global_load_lds(
        (const __attribute__((address_space(1))) void*)g,
        (__attribute__((address_space(3))) void*)l, 16, 0, 0);
}

// ---------------- convert w_qkv fp32 -> bf16
__global__ __launch_bounds__(256) void k_wcvt(const float* __restrict__ w,
                                              u16* __restrict__ wbf)
{
    const int i4 = (blockIdx.x * 256 + threadIdx.x) * 4;
    float4 v = *reinterpret_cast<const float4*>(w + i4);
    ushort4 s;
    s.x = f2bf(v.x); s.y = f2bf(v.y); s.z = f2bf(v.z); s.w = f2bf(v.w);
    *reinterpret_cast<ushort4*>(wbf + i4) = s;
}

// ---------------- transpose x [b][k=384][p] fp32 -> Xt [b][p][k=384] bf16
__global__ __launch_bounds__(256) void k_tr_x(const float* __restrict__ x,
                                              u16* __restrict__ xt)
{
    const int b = blockIdx.z;
    const int k0 = blockIdx.y * 64;
    const int p0 = blockIdx.x * 64;
    const int t = threadIdx.x;
    __shared__ u16 T[64][68];

    const int kl = t >> 4;          // 0..15
    const int pl = (t & 15) * 4;    // 0..60
#pragma unroll
    for (int ks = 0; ks < 4; ++ks) {
        const int k = ks * 16 + kl;
        float4 v = *reinterpret_cast<const float4*>(&x[((size_t)b * DIM + k0 + k) * PP + p0 + pl]);
        ushort4 s;
        s.x = f2bf(v.x); s.y = f2bf(v.y); s.z = f2bf(v.z); s.w = f2bf(v.w);
        *reinterpret_cast<ushort4*>(&T[k][pl]) = s;
    }
    __syncthreads();
    const int pr = t >> 2;          // 0..63
    const int kg = (t & 3) * 16;    // 0,16,32,48
    __align__(16) u16 tmp[16];
#pragma unroll
    for (int j = 0; j < 16; ++j) tmp[j] = T[kg + j][pr];
    u16* dst = xt + ((size_t)b * PP + p0 + pr) * DIM + k0 + kg;
    *reinterpret_cast<uint4*>(dst)     = *reinterpret_cast<uint4*>(tmp);
    *reinterpret_cast<uint4*>(dst + 8) = *reinterpret_cast<uint4*>(tmp + 8);
}

// ---------------- MFMA GEMM: C[b][co][p] = sum_k A[(b)][co][k] * Bt[b][p][k]
// MODE 0: += bias, write bf16 ybf.  MODE 1: += bias + xres, write fp32 fout.
// Staging via global_load_lds(16B) with pre-swizzled per-lane GLOBAL source.
template<int MODE>
__global__ __launch_bounds__(256) void k_gemm(const u16* __restrict__ A, int aStride,
                                              const u16* __restrict__ Bt,
                                              const float* __restrict__ bias,
                                              u16* __restrict__ ybf,
                                              const float* __restrict__ xres,
                                              float* __restrict__ fout,
                                              int nyTiles)
{
    const int bid = blockIdx.x;
    const int xcd = bid & 7;
    const int r1  = bid >> 3;
    const int px  = xcd * 16 + (r1 & 15);   // p-tile 0..127
    const int r2  = r1 >> 4;
    const int b   = r2 / nyTiles;           // batch
    const int yt  = r2 - b * nyTiles;       // co-tile
    const int co0 = yt * 128;
    const int p0  = px * 128;

    const int t   = threadIdx.x;
    const int l   = t & 63;
    const int wid = t >> 6;
    const int wr  = wid >> 1;      // 0..1 -> row half
    const int wc  = wid & 1;       // 0..1 -> col half
    const int lr  = l & 15;
    const int lg  = l >> 4;        // 0..3

    __shared__ __align__(16) char lds[32768];
    char* AsB = lds;               // [128 rows][64 k] bf16, swizzled content
    char* BsB = lds + 16384;

    f32x4 acc[4][4];
#pragma unroll
    for (int m = 0; m < 4; ++m)
#pragma unroll
        for (int n = 0; n < 4; ++n) acc[m][n] = (f32x4){0.f, 0.f, 0.f, 0.f};

    const u16* Ab  = A  + (size_t)b * aStride;
    const u16* Btb = Bt + (size_t)b * PP * DIM;

    // per-lane source mapping for gld_lds16 (8 rows / wave-issue)
    const int lrow8 = l >> 3;                 // 0..7 within the 8-row group
    const int sl    = l & 7;                  // 16B slot 0..7 within 128B row

    for (int k0 = 0; k0 < DIM; k0 += 64) {
        if (k0) __syncthreads();   // prev iter's LDS reads complete
#pragma unroll
        for (int i = 0; i < 4; ++i) {
            const int rbase = wid * 32 + i * 8;
            const int row   = rbase + lrow8;
            const int elem  = (sl * 8) ^ ((row & 7) << 3);   // inverse swizzle
            gld_lds16(Ab  + (size_t)(co0 + row) * DIM + k0 + elem, AsB + rbase * 128);
            gld_lds16(Btb + (size_t)(p0  + row) * DIM + k0 + elem, BsB + rbase * 128);
        }
        __syncthreads();           // drains vmcnt(0) then barrier -> tiles ready

#pragma unroll
        for (int kk = 0; kk < 64; kk += 32) {
            const int kbyte = kk * 2 + lg * 16;
            bf16x8 av[4], bv[4];
#pragma unroll
            for (int m = 0; m < 4; ++m) {
                const int row = wr * 64 + m * 16 + lr;
                av[m] = *reinterpret_cast<const bf16x8*>(AsB + swz(row, kbyte));
            }
#pragma unroll
            for (int n = 0; n < 4; ++n) {
                const int row = wc * 64 + n * 16 + lr;
                bv[n] = *reinterpret_cast<const bf16x8*>(BsB + swz(row, kbyte));
            }
#pragma unroll
            for (int m = 0; m < 4; ++m)
#pragma unroll
                for (int n = 0; n < 4; ++n)
                    acc[m][n] = __builtin_amdgcn_mfma_f32_16x16x32_bf16(
                        av[m], bv[n], acc[m][n], 0, 0, 0);
        }
    }

    // bias per (m, r): row = wr*64 + m*16 + lg*4 + r
    float bias_r[4][4];
#pragma unroll
    for (int m = 0; m < 4; ++m)
#pragma unroll
        for (int r = 0; r < 4; ++r)
            bias_r[m][r] = bias[co0 + wr * 64 + m * 16 + lg * 4 + r];

    if (MODE == 0) {
        __syncthreads();
        u16* Cs = reinterpret_cast<u16*>(lds);
#pragma unroll
        for (int m = 0; m < 4; ++m)
#pragma unroll
            for (int n = 0; n < 4; ++n)
#pragma unroll
                for (int r = 0; r < 4; ++r) {
                    const int row = wr * 64 + m * 16 + lg * 4 + r;
                    const int col = wc * 64 + n * 16 + lr;
                    Cs[row * 128 + col] = f2bf(acc[m][n][r] + bias_r[m][r]);
                }
        __syncthreads();
        // coalesced store: 16 lanes cover one 256B row segment
        const int rr = t >> 4;          // 0..15
        const int cs = (t & 15) * 8;    // u16 col
#pragma unroll
        for (int j = 0; j < 8; ++j) {
            const int row = j * 16 + rr;
            *reinterpret_cast<uint4*>(&ybf[((size_t)b * DIM3 + co0 + row) * PP + p0 + cs]) =
                *reinterpret_cast<const uint4*>(&Cs[row * 128 + cs]);
        }
    } else {
        // fp32 epilogue via LDS in two 64-row half-passes
        float* Cf = reinterpret_cast<float*>(lds);
#pragma unroll
        for (int h = 0; h < 2; ++h) {
            __syncthreads();
            if (wr == h) {
#pragma unroll
                for (int m = 0; m < 4; ++m)
#pragma unroll
                    for (int n = 0; n < 4; ++n)
#pragma unroll
                        for (int r = 0; r < 4; ++r) {
                            const int lrow = m * 16 + lg * 4 + r;
                            const int col = wc * 64 + n * 16 + lr;
                            Cf[lrow * 128 + col] = acc[m][n][r] + bias_r[m][r];
                        }
            }
            __syncthreads();
            const int rr = t >> 5;          // 0..7
            const int cc = (t & 31) * 4;    // fp32 col
#pragma unroll
            for (int j = 0; j < 8; ++j) {
                const int lrow = j * 8 + rr;
                const int grow = h * 64 + lrow;
                const size_t idx = ((size_t)b * DIM + co0 + grow) * PP + p0 + cc;
                float4 xr = *reinterpret_cast<const float4*>(&xres[idx]);
                float4 cv = *reinterpret_cast<const float4*>(&Cf[lrow * 128 + cc]);
                cv.x += xr.x; cv.y += xr.y; cv.z += xr.z; cv.w += xr.w;
                *reinterpret_cast<float4*>(&fout[idx]) = cv;
            }
        }
    }
}

// ---------------- fused dw(v) + transpose -> vt[b][p][c], strip-mined v2
// Block = 4-row band x 128 cols x 32 channels. Threads 256 = 32ch x 8 strips(16px).
#define LOADROW3(arr, gr_)                                                     \
    {                                                                          \
        const int r_ = (gr_);                                                  \
        if (r_ >= 0 && r_ < HH) {                                              \
            union { uint4 v; u16 u[8]; } a0_, a1_;                             \
            a0_.v = *reinterpret_cast<const uint4*>(img + r_ * WW2 + c0);      \
            a1_.v = *reinterpret_cast<const uint4*>(img + r_ * WW2 + c0 + 8);  \
            arr[1] = bf2f(a0_.u[0]); arr[2] = bf2f(a0_.u[1]);                  \
            arr[3] = bf2f(a0_.u[2]); arr[4] = bf2f(a0_.u[3]);                  \
            arr[5] = bf2f(a0_.u[4]); arr[6] = bf2f(a0_.u[5]);                  \
            arr[7] = bf2f(a0_.u[6]); arr[8] = bf2f(a0_.u[7]);                  \
            arr[9]  = bf2f(a1_.u[0]); arr[10] = bf2f(a1_.u[1]);                \
            arr[11] = bf2f(a1_.u[2]); arr[12] = bf2f(a1_.u[3]);                \
            arr[13] = bf2f(a1_.u[4]); arr[14] = bf2f(a1_.u[5]);                \
            arr[15] = bf2f(a1_.u[6]); arr[16] = bf2f(a1_.u[7]);                \
        } else {                                                               \
            for (int z_ = 1; z_ <= 16; ++z_) arr[z_] = 0.f;                    \
        }                                                                      \
        float lf_ = __shfl(arr[16], t - 1);                                    \
        float rt_ = __shfl(arr[1],  t + 1);                                    \
        arr[0]  = (s > 0) ? lf_ : 0.f;                                         \
        arr[17] = (s < 7) ? rt_ : 0.f;                                         \
    }

__global__ __launch_bounds__(256) void k_dwtr(const u16* __restrict__ y1,
                                              const float* __restrict__ wdw,
                                              const float* __restrict__ bdw,
                                              u16* __restrict__ vt)
{
    const int band = blockIdx.x;   // 0..31 (4-row bands)
    const int chg  = blockIdx.y;   // 0..11 (32-ch groups)
    const int b    = blockIdx.z;
    const int t    = (int)threadIdx.x;
    const int ch   = t >> 3;       // 0..31
    const int s    = t & 7;        // 16-px strip
    const int c0   = s * 16;
    const int r0   = band * 4;

    const int gch = 2 * DIM + chg * 32 + ch;
    const u16* img = y1 + ((size_t)b * DIM3 + gch) * PP;

    float w9[9];
#pragma unroll
    for (int i = 0; i < 9; ++i) w9[i] = wdw[gch * 9 + i];
    const float bv = bdw[gch];

    // [ch][4*128 px + 8 pad]: row stride 1040B (16B-aligned, 4-bank ch skew)
    __shared__ __align__(16) u16 T[32][520];

    float A[18], B[18], C[18];
    LOADROW3(A, r0 - 1);
    LOADROW3(B, r0);

#pragma unroll
    for (int j = 0; j < 4; ++j) {
        LOADROW3(C, r0 + j + 1);
        union { uint4 v[2]; u16 u[16]; } og;
#pragma unroll
        for (int cidx = 0; cidx < 16; ++cidx) {
            float a = bv;
            a = fmaf(w9[0], A[cidx],     a);
            a = fmaf(w9[1], A[cidx + 1], a);
            a = fmaf(w9[2], A[cidx + 2], a);
            a = fmaf(w9[3], B[cidx],     a);
            a = fmaf(w9[4], B[cidx + 1], a);
            a = fmaf(w9[5], B[cidx + 2], a);
            a = fmaf(w9[6], C[cidx],     a);
            a = fmaf(w9[7], C[cidx + 1], a);
            a = fmaf(w9[8], C[cidx + 2], a);
            og.u[cidx] = f2bf(a);
        }
        *reinterpret_cast<uint4*>(&T[ch][j * 128 + c0])     = og.v[0];
        *reinterpret_cast<uint4*>(&T[ch][j * 128 + c0 + 8]) = og.v[1];
#pragma unroll
        for (int q = 0; q < 18; ++q) { A[q] = B[q]; B[q] = C[q]; }
    }
    __syncthreads();

    // transpose store: lane = px, gather 32 ch (conflict-free), 64B/px line
#pragma unroll
    for (int j = 0; j < 2; ++j) {
        const int px = j * 256 + t;           // 0..511
        union { uint4 v[4]; u16 u[32]; } ov;
#pragma unroll
        for (int c2 = 0; c2 < 32; ++c2) ov.u[c2] = T[c2][px];
        u16* dst = vt + ((size_t)b * PP + band * 512 + px) * DIM + chg * 32;
        *reinterpret_cast<uint4*>(dst)      = ov.v[0];
        *reinterpret_cast<uint4*>(dst + 8)  = ov.v[1];
        *reinterpret_cast<uint4*>(dst + 16) = ov.v[2];
        *reinterpret_cast<uint4*>(dst + 24) = ov.v[3];
    }
}

// halo load for k_dwqk: 8 px strip on one row, shuffles for column halo
#define LOADROW2(arr, gr_)                                                     \
    {                                                                          \
        const int r_ = (gr_);                                                  \
        if (r_ >= 0 && r_ < HH) {                                              \
            union { uint4 v; u16 u[8]; } cc_;                                  \
            cc_.v = *reinterpret_cast<const uint4*>(img + r_ * WW2 + sp);      \
            arr[1] = bf2f(cc_.u[0]); arr[2] = bf2f(cc_.u[1]);                  \
            arr[3] = bf2f(cc_.u[2]); arr[4] = bf2f(cc_.u[3]);                  \
            arr[5] = bf2f(cc_.u[4]); arr[6] = bf2f(cc_.u[5]);                  \
            arr[7] = bf2f(cc_.u[6]); arr[8] = bf2f(cc_.u[7]);                  \
        } else {                                                               \
            arr[1] = 0.f; arr[2] = 0.f; arr[3] = 0.f; arr[4] = 0.f;            \
            arr[5] = 0.f; arr[6] = 0.f; arr[7] = 0.f; arr[8] = 0.f;            \
        }                                                                      \
        float lf_ = __shfl(arr[8], t - 1);                                     \
        float rt_ = __shfl(arr[1], t + 1);                                     \
        arr[0] = (s > 0)  ? lf_ : 0.f;                                         \
        arr[9] = (s < 15) ? rt_ : 0.f;                                         \
    }

// ---------------- fused dw(q,k) + MFMA self-Gram. Block = (c, band of 8 rows, b).
__global__ __launch_bounds__(256) void k_dwqk(const u16* __restrict__ y1,
                                              const float* __restrict__ wdw,
                                              const float* __restrict__ bdw,
                                              float* __restrict__ partial)
{
    const int c    = blockIdx.x;   // 0..47
    const int band = blockIdx.y;   // 0..15
    const int b    = blockIdx.z;   // 0..3
    const int t    = (int)threadIdx.x;
    const int h    = t >> 7;       // 0=q set, 1=k set (wave-uniform)
    const int r    = (t >> 4) & 7; // row within band
    const int s    = t & 15;       // 8-px strip
    const int sp   = s * 8;
    const int r0   = band * 8;

    __shared__ __align__(16) u16 G[16][1032];    // 16 x (1024 + 8 pad) bf16 = 33KB
    __shared__ __align__(16) float red[4][256];  // 4KB

#pragma unroll
    for (int n = 0; n < 8; ++n) {
        const int gch = h * DIM + n * CPG + c;
        const u16* img = y1 + ((size_t)b * DIM3 + gch) * PP;
        float w9[9];
#pragma unroll
        for (int i = 0; i < 9; ++i) w9[i] = wdw[gch * 9 + i];
        const float bv = bdw[gch];

        float A[10], B[10], C[10];
        LOADROW2(A, r0 + r - 1);
        LOADROW2(B, r0 + r);
        LOADROW2(C, r0 + r + 1);

        union { uint4 v; u16 u[8]; } og;
#pragma unroll
        for (int j = 0; j < 8; ++j) {
            float a = bv;
            a = fmaf(w9[0], A[j],     a);
            a = fmaf(w9[1], A[j + 1], a);
            a = fmaf(w9[2], A[j + 2], a);
            a = fmaf(w9[3], B[j],     a);
            a = fmaf(w9[4], B[j + 1], a);
            a = fmaf(w9[5], B[j + 2], a);
            a = fmaf(w9[6], C[j],     a);
            a = fmaf(w9[7], C[j + 1], a);
            a = fmaf(w9[8], C[j + 2], a);
            og.u[j] = f2bf(a);
        }
        *reinterpret_cast<uint4*>(&G[h * 8 + n][r * 128 + sp]) = og.v;
    }
    __syncthreads();

    // Gram: wave w covers K range [w*256, w*256+256)
    const int l = t & 63, w = t >> 6;
    const int grow = l & 15;
    const int koc  = (l >> 4) * 8;
    f32x4 acc = (f32x4){0.f, 0.f, 0.f, 0.f};
#pragma unroll
    for (int q8 = 0; q8 < 8; ++q8) {
        const int koff = w * 256 + q8 * 32 + koc;
        bf16x8 g = *reinterpret_cast<const bf16x8*>(&G[grow][koff]);
        acc = __builtin_amdgcn_mfma_f32_16x16x32_bf16(g, g, acc, 0, 0, 0);
    }
    // C/D layout: col = lane&15, row = (lane>>4)*4 + reg  ->  S[row][col]
#pragma unroll
    for (int rg = 0; rg < 4; ++rg)
        red[w][((l >> 4) * 4 + rg) * 16 + (l & 15)] = acc[rg];
    __syncthreads();

    const float sum = red[0][t] + red[1][t] + red[2][t] + red[3][t];
    partial[((size_t)((b * 48 + c) * 16 + band)) * 256 + t] = sum;
}

// ---------------- stage-A reduce: 768 partial rows -> 16 rows per batch
__global__ __launch_bounds__(256) void k_red(const float* __restrict__ partial,
                                             float* __restrict__ p2)
{
    const int g = blockIdx.x;      // 0..15
    const int b = blockIdx.y;
    const int t = threadIdx.x;
    const float* base = partial + ((size_t)b * 768 + g * 48) * 256 + t;
    float s = 0.f;
#pragma unroll 4
    for (int i = 0; i < 48; ++i) s += base[(size_t)i * 256];
    p2[((size_t)b * 16 + g) * 256 + t] = s;
}

// ---------------- stage-B: sum 16 rows, normalize, softmax -> attn[b][8][8]
__global__ __launch_bounds__(256) void k_attn(const float* __restrict__ p2,
                                              const float* __restrict__ temp,
                                              float* __restrict__ attn)
{
    const int b = blockIdx.x;
    const int t = threadIdx.x;
    __shared__ float S[256];
    __shared__ float sc[8][8];
    float s = 0.f;
#pragma unroll
    for (int i = 0; i < 16; ++i)
        s += p2[((size_t)b * 16 + i) * 256 + t];
    S[t] = s;
    __syncthreads();
    if (t < 64) {
        const int n = t >> 3, m = t & 7;
        const float qn = fmaxf(sqrtf(S[n * 16 + n]), 1e-12f);
        const float km = fmaxf(sqrtf(S[(8 + m) * 16 + 8 + m]), 1e-12f);
        sc[n][m] = S[n * 16 + 8 + m] / (qn * km) * temp[0];
    }
    __syncthreads();
    if (t < 8) {
        float mx = -3.0e38f;
#pragma unroll
        for (int m = 0; m < 8; ++m) mx = fmaxf(mx, sc[t][m]);
        float e[8], ssum = 0.f;
#pragma unroll
        for (int m = 0; m < 8; ++m) { e[m] = expf(sc[t][m] - mx); ssum += e[m]; }
        const float inv = 1.f / ssum;
#pragma unroll
        for (int m = 0; m < 8; ++m) attn[(b * 8 + t) * 8 + m] = e[m] * inv;
    }
}

// ---------------- Weff[b][co][m*48+c] = sum_n wproj[co][n*48+c]*attn[n][m]  (bf16 out)
__global__ __launch_bounds__(128) void k_weff(const float* __restrict__ attn,
                                              const float* __restrict__ wproj,
                                              u16* __restrict__ weff)
{
    const int b  = blockIdx.y;
    const int co = blockIdx.x;
    const int t  = threadIdx.x;
    __shared__ float a[64];
    if (t < 64) a[t] = attn[b * 64 + t];
    __syncthreads();
    const float* wrow = wproj + (size_t)co * DIM;
    u16* wout = weff + ((size_t)b * DIM + co) * DIM;
    for (int i = t; i < DIM; i += 128) {
        const int m = i / CPG;
        const int c = i - m * CPG;
        float s = 0.f;
#pragma unroll
        for (int n = 0; n < 8; ++n) s += wrow[n * CPG + c] * a[n * 8 + m];
        wout[i] = f2bf(s);
    }
}

extern "C" void kernel_launch(void* const* d_in, const int* in_sizes, int n_in,
                              void* d_out, int out_size, void* d_ws, size_t ws_size,
                              hipStream_t stream)
{
    const float* x      = (const float*)d_in[0];
    const float* temp   = (const float*)d_in[1];
    const float* w_qkv  = (const float*)d_in[2];
    const float* b_qkv  = (const float*)d_in[3];
    const float* w_dw   = (const float*)d_in[4];
    const float* b_dw   = (const float*)d_in[5];
    const float* w_proj = (const float*)d_in[6];
    const float* b_proj = (const float*)d_in[7];
    float* out = (float*)d_out;

    char* ws = (char*)d_ws;
    const size_t SZ_QKV = (size_t)BB * DIM3 * PP * sizeof(u16);  // 150,994,944
    const size_t SZ_XT  = (size_t)BB * PP * DIM * sizeof(u16);   //  50,331,648

    // region 0: [0, SZ_QKV) -- y1 (gemm0 out; read by k_dwtr/k_dwqk)
    u16* y1 = (u16*)ws;

    // region 1: [SZ_QKV, 2*SZ_QKV)
    u16* xt  = (u16*)(ws + SZ_QKV);               // pre-gemm0 only
    u16* wbf = (u16*)(ws + SZ_QKV + SZ_XT);       // pre-gemm0 only
    // after gemm0 (xt/wbf dead):
    float* partial = (float*)(ws + SZ_QKV);              // 3,145,728 B
    float* attn    = (float*)(ws + SZ_QKV + 3145728);    // 1,024 B
    u16*   weffb   = (u16*)(ws + SZ_QKV + 3211264);      // 1,179,648 B
    float* p2      = (float*)(ws + SZ_QKV + 4456448);    // 65,536 B (ends ~4.5MB)
    u16*   vt      = (u16*)(ws + SZ_QKV + 8388608);      // 50.3MB (ends ~58.7MB)

    k_wcvt<<<dim3(DIM3 * DIM / 1024), 256, 0, stream>>>(w_qkv, wbf);
    k_tr_x<<<dim3(PP / 64, DIM / 64, BB), 256, 0, stream>>>(x, xt);
    k_gemm<0><<<dim3(128 * 9 * BB), 256, 0, stream>>>(
        wbf, 0, xt, b_qkv, y1, nullptr, nullptr, 9);
    k_dwtr<<<dim3(32, 12, BB), 256, 0, stream>>>(y1, w_dw, b_dw, vt);
    k_dwqk<<<dim3(48, 16, BB), 256, 0, stream>>>(y1, w_dw, b_dw, partial);
    k_red<<<dim3(16, BB), 256, 0, stream>>>(partial, p2);
    k_attn<<<dim3(BB), 256, 0, stream>>>(p2, temp, attn);
    k_weff<<<dim3(DIM, BB), 128, 0, stream>>>(attn, w_proj, weffb);
    k_gemm<1><<<dim3(128 * 3 * BB), 256, 0, stream>>>(
        weffb, DIM * DIM, vt, b_proj, nullptr, x, out, 3);
}

// Round 18
// 248.266 us; speedup vs baseline: 1.1538x; 1.0178x over previous
//
#include <hip/hip_runtime.h>
#include <hip/hip_bf16.h>

#define BB 4
#define CPG 48
#define HH 128
#define WW2 128
#define PP 16384
#define DIM 384
#define DIM3 1152

typedef unsigned short u16;
typedef __attribute__((ext_vector_type(8))) short bf16x8;
typedef __attribute__((ext_vector_type(4))) float f32x4;

__device__ __forceinline__ float bf2f(u16 u) {
    return __uint_as_float(((unsigned int)u) << 16);
}
__device__ __forceinline__ u16 f2bf(float f) {
    unsigned int u = __float_as_uint(f);
    unsigned int r = (u + 0x7fffu + ((u >> 16) & 1u)) >> 16;
    return (u16)r;
}

// LDS swizzle: rows are 128B; XOR the 16B-slot index with (row&7) to spread banks
__device__ __forceinline__ int swz(int row, int kb) {
    return row * 128 + (kb ^ ((row & 7) << 4));
}

// async global->LDS, 16B per lane; LDS dest = wave-uniform base + lane*16
__device__ __forceinline__ void gld_lds16(const u16* g, char* l) {
    __builtin_amdgcn_global_load_lds(
        (const __attribute__((address_space(1))) void*)g,
        (__attribute__((address_space(3))) void*)l, 16, 0, 0);
}

// ---------------- transpose x [b][k=384][p] fp32 -> Xt [b][p][k=384] bf16
// (+ first 432 flat blocks also convert w_qkv fp32 -> bf16)
__global__ __launch_bounds__(256) void k_tr_x(const float* __restrict__ x,
                                              u16* __restrict__ xt,
                                              const float* __restrict__ w,
                                              u16* __restrict__ wbf)
{
    const int b = blockIdx.z;
    const int k0 = blockIdx.y * 64;
    const int p0 = blockIdx.x * 64;
    const int t = threadIdx.x;
    __shared__ u16 T[64][68];

    // side job: w_qkv convert (432 blocks x 1024 elems = 442,368)
    const int fb = (blockIdx.z * 6 + blockIdx.y) * 256 + blockIdx.x;
    if (fb < 432) {
        const int i4 = (fb * 256 + t) * 4;
        float4 v = *reinterpret_cast<const float4*>(w + i4);
        ushort4 s;
        s.x = f2bf(v.x); s.y = f2bf(v.y); s.z = f2bf(v.z); s.w = f2bf(v.w);
        *reinterpret_cast<ushort4*>(wbf + i4) = s;
    }

    const int kl = t >> 4;          // 0..15
    const int pl = (t & 15) * 4;    // 0..60
#pragma unroll
    for (int ks = 0; ks < 4; ++ks) {
        const int k = ks * 16 + kl;
        float4 v = *reinterpret_cast<const float4*>(&x[((size_t)b * DIM + k0 + k) * PP + p0 + pl]);
        ushort4 s;
        s.x = f2bf(v.x); s.y = f2bf(v.y); s.z = f2bf(v.z); s.w = f2bf(v.w);
        *reinterpret_cast<ushort4*>(&T[k][pl]) = s;
    }
    __syncthreads();
    const int pr = t >> 2;          // 0..63
    const int kg = (t & 3) * 16;    // 0,16,32,48
    __align__(16) u16 tmp[16];
#pragma unroll
    for (int j = 0; j < 16; ++j) tmp[j] = T[kg + j][pr];
    u16* dst = xt + ((size_t)b * PP + p0 + pr) * DIM + k0 + kg;
    *reinterpret_cast<uint4*>(dst)     = *reinterpret_cast<uint4*>(tmp);
    *reinterpret_cast<uint4*>(dst + 8) = *reinterpret_cast<uint4*>(tmp + 8);
}

// ---------------- MFMA GEMM: C[b][co][p] = sum_k A[(b)][co][k] * Bt[b][p][k]
// MODE 0: += bias, write bf16 ybf.  MODE 1: += bias + xres, write fp32 fout.
// Staging via global_load_lds(16B) with pre-swizzled per-lane GLOBAL source.
template<int MODE>
__global__ __launch_bounds__(256) void k_gemm(const u16* __restrict__ A, int aStride,
                                              const u16* __restrict__ Bt,
                                              const float* __restrict__ bias,
                                              u16* __restrict__ ybf,
                                              const float* __restrict__ xres,
                                              float* __restrict__ fout,
                                              int nyTiles)
{
    const int bid = blockIdx.x;
    const int xcd = bid & 7;
    const int r1  = bid >> 3;
    const int px  = xcd * 16 + (r1 & 15);   // p-tile 0..127
    const int r2  = r1 >> 4;
    const int b   = r2 / nyTiles;           // batch
    const int yt  = r2 - b * nyTiles;       // co-tile
    const int co0 = yt * 128;
    const int p0  = px * 128;

    const int t   = threadIdx.x;
    const int l   = t & 63;
    const int wid = t >> 6;
    const int wr  = wid >> 1;      // 0..1 -> row half
    const int wc  = wid & 1;       // 0..1 -> col half
    const int lr  = l & 15;
    const int lg  = l >> 4;        // 0..3

    __shared__ __align__(16) char lds[32768];
    char* AsB = lds;               // [128 rows][64 k] bf16, swizzled content
    char* BsB = lds + 16384;

    f32x4 acc[4][4];
#pragma unroll
    for (int m = 0; m < 4; ++m)
#pragma unroll
        for (int n = 0; n < 4; ++n) acc[m][n] = (f32x4){0.f, 0.f, 0.f, 0.f};

    const u16* Ab  = A  + (size_t)b * aStride;
    const u16* Btb = Bt + (size_t)b * PP * DIM;

    // per-lane source mapping for gld_lds16 (8 rows / wave-issue)
    const int lrow8 = l >> 3;                 // 0..7 within the 8-row group
    const int sl    = l & 7;                  // 16B slot 0..7 within 128B row

    for (int k0 = 0; k0 < DIM; k0 += 64) {
        if (k0) __syncthreads();   // prev iter's LDS reads complete
#pragma unroll
        for (int i = 0; i < 4; ++i) {
            const int rbase = wid * 32 + i * 8;
            const int row   = rbase + lrow8;
            const int elem  = (sl * 8) ^ ((row & 7) << 3);   // inverse swizzle
            gld_lds16(Ab  + (size_t)(co0 + row) * DIM + k0 + elem, AsB + rbase * 128);
            gld_lds16(Btb + (size_t)(p0  + row) * DIM + k0 + elem, BsB + rbase * 128);
        }
        __syncthreads();           // drains vmcnt(0) then barrier -> tiles ready

#pragma unroll
        for (int kk = 0; kk < 64; kk += 32) {
            const int kbyte = kk * 2 + lg * 16;
            bf16x8 av[4], bv[4];
#pragma unroll
            for (int m = 0; m < 4; ++m) {
                const int row = wr * 64 + m * 16 + lr;
                av[m] = *reinterpret_cast<const bf16x8*>(AsB + swz(row, kbyte));
            }
#pragma unroll
            for (int n = 0; n < 4; ++n) {
                const int row = wc * 64 + n * 16 + lr;
                bv[n] = *reinterpret_cast<const bf16x8*>(BsB + swz(row, kbyte));
            }
#pragma unroll
            for (int m = 0; m < 4; ++m)
#pragma unroll
                for (int n = 0; n < 4; ++n)
                    acc[m][n] = __builtin_amdgcn_mfma_f32_16x16x32_bf16(
                        av[m], bv[n], acc[m][n], 0, 0, 0);
        }
    }

    // bias per (m, r): row = wr*64 + m*16 + lg*4 + r
    float bias_r[4][4];
#pragma unroll
    for (int m = 0; m < 4; ++m)
#pragma unroll
        for (int r = 0; r < 4; ++r)
            bias_r[m][r] = bias[co0 + wr * 64 + m * 16 + lg * 4 + r];

    if (MODE == 0) {
        __syncthreads();
        u16* Cs = reinterpret_cast<u16*>(lds);
#pragma unroll
        for (int m = 0; m < 4; ++m)
#pragma unroll
            for (int n = 0; n < 4; ++n)
#pragma unroll
                for (int r = 0; r < 4; ++r) {
                    const int row = wr * 64 + m * 16 + lg * 4 + r;
                    const int col = wc * 64 + n * 16 + lr;
                    Cs[row * 128 + col] = f2bf(acc[m][n][r] + bias_r[m][r]);
                }
        __syncthreads();
        // coalesced store: 16 lanes cover one 256B row segment
        const int rr = t >> 4;          // 0..15
        const int cs = (t & 15) * 8;    // u16 col
#pragma unroll
        for (int j = 0; j < 8; ++j) {
            const int row = j * 16 + rr;
            *reinterpret_cast<uint4*>(&ybf[((size_t)b * DIM3 + co0 + row) * PP + p0 + cs]) =
                *reinterpret_cast<const uint4*>(&Cs[row * 128 + cs]);
        }
    } else {
        // fp32 epilogue via LDS in two 64-row half-passes
        float* Cf = reinterpret_cast<float*>(lds);
#pragma unroll
        for (int h = 0; h < 2; ++h) {
            __syncthreads();
            if (wr == h) {
#pragma unroll
                for (int m = 0; m < 4; ++m)
#pragma unroll
                    for (int n = 0; n < 4; ++n)
#pragma unroll
                        for (int r = 0; r < 4; ++r) {
                            const int lrow = m * 16 + lg * 4 + r;
                            const int col = wc * 64 + n * 16 + lr;
                            Cf[lrow * 128 + col] = acc[m][n][r] + bias_r[m][r];
                        }
            }
            __syncthreads();
            const int rr = t >> 5;          // 0..7
            const int cc = (t & 31) * 4;    // fp32 col
#pragma unroll
            for (int j = 0; j < 8; ++j) {
                const int lrow = j * 8 + rr;
                const int grow = h * 64 + lrow;
                const size_t idx = ((size_t)b * DIM + co0 + grow) * PP + p0 + cc;
                float4 xr = *reinterpret_cast<const float4*>(&xres[idx]);
                float4 cv = *reinterpret_cast<const float4*>(&Cf[lrow * 128 + cc]);
                cv.x += xr.x; cv.y += xr.y; cv.z += xr.z; cv.w += xr.w;
                *reinterpret_cast<float4*>(&fout[idx]) = cv;
            }
        }
    }
}

// halo loads
#define LOADROW3(arr, gr_)                                                     \
    {                                                                          \
        const int r_ = (gr_);                                                  \
        if (r_ >= 0 && r_ < HH) {                                              \
            union { uint4 v; u16 u[8]; } a0_, a1_;                             \
            a0_.v = *reinterpret_cast<const uint4*>(img + r_ * WW2 + c0);      \
            a1_.v = *reinterpret_cast<const uint4*>(img + r_ * WW2 + c0 + 8);  \
            arr[1] = bf2f(a0_.u[0]); arr[2] = bf2f(a0_.u[1]);                  \
            arr[3] = bf2f(a0_.u[2]); arr[4] = bf2f(a0_.u[3]);                  \
            arr[5] = bf2f(a0_.u[4]); arr[6] = bf2f(a0_.u[5]);                  \
            arr[7] = bf2f(a0_.u[6]); arr[8] = bf2f(a0_.u[7]);                  \
            arr[9]  = bf2f(a1_.u[0]); arr[10] = bf2f(a1_.u[1]);                \
            arr[11] = bf2f(a1_.u[2]); arr[12] = bf2f(a1_.u[3]);                \
            arr[13] = bf2f(a1_.u[4]); arr[14] = bf2f(a1_.u[5]);                \
            arr[15] = bf2f(a1_.u[6]); arr[16] = bf2f(a1_.u[7]);                \
        } else {                                                               \
            for (int z_ = 1; z_ <= 16; ++z_) arr[z_] = 0.f;                    \
        }                                                                      \
        float lf_ = __shfl(arr[16], t - 1);                                    \
        float rt_ = __shfl(arr[1],  t + 1);                                    \
        arr[0]  = (s > 0) ? lf_ : 0.f;                                         \
        arr[17] = (s < 7) ? rt_ : 0.f;                                         \
    }

#define LOADROW2(arr, gr_)                                                     \
    {                                                                          \
        const int r_ = (gr_);                                                  \
        if (r_ >= 0 && r_ < HH) {                                              \
            union { uint4 v; u16 u[8]; } cc_;                                  \
            cc_.v = *reinterpret_cast<const uint4*>(img + r_ * WW2 + sp);      \
            arr[1] = bf2f(cc_.u[0]); arr[2] = bf2f(cc_.u[1]);                  \
            arr[3] = bf2f(cc_.u[2]); arr[4] = bf2f(cc_.u[3]);                  \
            arr[5] = bf2f(cc_.u[4]); arr[6] = bf2f(cc_.u[5]);                  \
            arr[7] = bf2f(cc_.u[6]); arr[8] = bf2f(cc_.u[7]);                  \
        } else {                                                               \
            arr[1] = 0.f; arr[2] = 0.f; arr[3] = 0.f; arr[4] = 0.f;            \
            arr[5] = 0.f; arr[6] = 0.f; arr[7] = 0.f; arr[8] = 0.f;            \
        }                                                                      \
        float lf_ = __shfl(arr[8], t - 1);                                     \
        float rt_ = __shfl(arr[1], t + 1);                                     \
        arr[0] = (s > 0)  ? lf_ : 0.f;                                         \
        arr[9] = (s < 15) ? rt_ : 0.f;                                         \
    }

// ---------------- merged dw kernel: id<384 -> dw(v)+transpose; else dw(q,k)+Gram
__global__ __launch_bounds__(256) void k_dw2(const u16* __restrict__ y1,
                                             const float* __restrict__ wdw,
                                             const float* __restrict__ bdw,
                                             u16* __restrict__ vt,
                                             float* __restrict__ partial)
{
    __shared__ __align__(16) char lds[37120];
    const int id = blockIdx.x;     // 0..1151
    const int b  = blockIdx.y;
    const int t  = (int)threadIdx.x;

    if (id < 384) {
        // ---- dw(v) + transpose (dwtr v2) ----
        const int band = id & 31;      // 4-row band
        const int chg  = id >> 5;      // 32-ch group 0..11
        const int ch   = t >> 3;       // 0..31
        const int s    = t & 7;        // 16-px strip
        const int c0   = s * 16;
        const int r0   = band * 4;

        const int gch = 2 * DIM + chg * 32 + ch;
        const u16* img = y1 + ((size_t)b * DIM3 + gch) * PP;

        float w9[9];
#pragma unroll
        for (int i = 0; i < 9; ++i) w9[i] = wdw[gch * 9 + i];
        const float bv = bdw[gch];

        u16 (*T)[520] = reinterpret_cast<u16(*)[520]>(lds);   // [32][520]

        float A[18], B[18], C[18];
        LOADROW3(A, r0 - 1);
        LOADROW3(B, r0);

#pragma unroll
        for (int j = 0; j < 4; ++j) {
            LOADROW3(C, r0 + j + 1);
            union { uint4 v[2]; u16 u[16]; } og;
#pragma unroll
            for (int cidx = 0; cidx < 16; ++cidx) {
                float a = bv;
                a = fmaf(w9[0], A[cidx],     a);
                a = fmaf(w9[1], A[cidx + 1], a);
                a = fmaf(w9[2], A[cidx + 2], a);
                a = fmaf(w9[3], B[cidx],     a);
                a = fmaf(w9[4], B[cidx + 1], a);
                a = fmaf(w9[5], B[cidx + 2], a);
                a = fmaf(w9[6], C[cidx],     a);
                a = fmaf(w9[7], C[cidx + 1], a);
                a = fmaf(w9[8], C[cidx + 2], a);
                og.u[cidx] = f2bf(a);
            }
            *reinterpret_cast<uint4*>(&T[ch][j * 128 + c0])     = og.v[0];
            *reinterpret_cast<uint4*>(&T[ch][j * 128 + c0 + 8]) = og.v[1];
#pragma unroll
            for (int q = 0; q < 18; ++q) { A[q] = B[q]; B[q] = C[q]; }
        }
        __syncthreads();

#pragma unroll
        for (int j = 0; j < 2; ++j) {
            const int px = j * 256 + t;
            union { uint4 v[4]; u16 u[32]; } ov;
#pragma unroll
            for (int c2 = 0; c2 < 32; ++c2) ov.u[c2] = T[c2][px];
            u16* dst = vt + ((size_t)b * PP + band * 512 + px) * DIM + chg * 32;
            *reinterpret_cast<uint4*>(dst)      = ov.v[0];
            *reinterpret_cast<uint4*>(dst + 8)  = ov.v[1];
            *reinterpret_cast<uint4*>(dst + 16) = ov.v[2];
            *reinterpret_cast<uint4*>(dst + 24) = ov.v[3];
        }
    } else {
        // ---- dw(q,k) + MFMA self-Gram (dwqk) ----
        const int id2  = id - 384;
        const int c    = id2 % 48;
        const int band = id2 / 48;     // 0..15
        const int h    = t >> 7;
        const int r    = (t >> 4) & 7;
        const int s    = t & 15;
        const int sp   = s * 8;
        const int r0   = band * 8;

        u16 (*G)[1032] = reinterpret_cast<u16(*)[1032]>(lds);         // [16][1032]
        float (*red)[256] = reinterpret_cast<float(*)[256]>(lds + 33024); // [4][256]

#pragma unroll
        for (int n = 0; n < 8; ++n) {
            const int gch = h * DIM + n * CPG + c;
            const u16* img = y1 + ((size_t)b * DIM3 + gch) * PP;
            float w9[9];
#pragma unroll
            for (int i = 0; i < 9; ++i) w9[i] = wdw[gch * 9 + i];
            const float bv = bdw[gch];

            float A[10], B[10], C[10];
            LOADROW2(A, r0 + r - 1);
            LOADROW2(B, r0 + r);
            LOADROW2(C, r0 + r + 1);

            union { uint4 v; u16 u[8]; } og;
#pragma unroll
            for (int j = 0; j < 8; ++j) {
                float a = bv;
                a = fmaf(w9[0], A[j],     a);
                a = fmaf(w9[1], A[j + 1], a);
                a = fmaf(w9[2], A[j + 2], a);
                a = fmaf(w9[3], B[j],     a);
                a = fmaf(w9[4], B[j + 1], a);
                a = fmaf(w9[5], B[j + 2], a);
                a = fmaf(w9[6], C[j],     a);
                a = fmaf(w9[7], C[j + 1], a);
                a = fmaf(w9[8], C[j + 2], a);
                og.u[j] = f2bf(a);
            }
            *reinterpret_cast<uint4*>(&G[h * 8 + n][r * 128 + sp]) = og.v;
        }
        __syncthreads();

        const int l = t & 63, w = t >> 6;
        const int grow = l & 15;
        const int koc  = (l >> 4) * 8;
        f32x4 acc = (f32x4){0.f, 0.f, 0.f, 0.f};
#pragma unroll
        for (int q8 = 0; q8 < 8; ++q8) {
            const int koff = w * 256 + q8 * 32 + koc;
            bf16x8 g = *reinterpret_cast<const bf16x8*>(&G[grow][koff]);
            acc = __builtin_amdgcn_mfma_f32_16x16x32_bf16(g, g, acc, 0, 0, 0);
        }
#pragma unroll
        for (int rg = 0; rg < 4; ++rg)
            red[w][((l >> 4) * 4 + rg) * 16 + (l & 15)] = acc[rg];
        __syncthreads();

        const float sum = red[0][t] + red[1][t] + red[2][t] + red[3][t];
        partial[((size_t)((b * 48 + c) * 16 + band)) * 256 + t] = sum;
    }
}

// ---------------- stage-A reduce: 768 partial rows -> 16 rows per batch
__global__ __launch_bounds__(256) void k_red(const float* __restrict__ partial,
                                             float* __restrict__ p2)
{
    const int g = blockIdx.x;      // 0..15
    const int b = blockIdx.y;
    const int t = threadIdx.x;
    const float* base = partial + ((size_t)b * 768 + g * 48) * 256 + t;
    float s = 0.f;
#pragma unroll 4
    for (int i = 0; i < 48; ++i) s += base[(size_t)i * 256];
    p2[((size_t)b * 16 + g) * 256 + t] = s;
}

// ---------------- Weff (with in-block attn reconstruction from p2)
__global__ __launch_bounds__(256) void k_weff(const float* __restrict__ p2,
                                              const float* __restrict__ temp,
                                              const float* __restrict__ wproj,
                                              u16* __restrict__ weff)
{
    const int b  = blockIdx.y;
    const int co = blockIdx.x;
    const int t  = threadIdx.x;
    __shared__ float S[256];
    __shared__ float sc[8][8];
    __shared__ float a[64];

    float s = 0.f;
#pragma unroll
    for (int i = 0; i < 16; ++i)
        s += p2[((size_t)b * 16 + i) * 256 + t];
    S[t] = s;
    __syncthreads();
    if (t < 64) {
        const int n = t >> 3, m = t & 7;
        const float qn = fmaxf(sqrtf(S[n * 16 + n]), 1e-12f);
        const float km = fmaxf(sqrtf(S[(8 + m) * 16 + 8 + m]), 1e-12f);
        sc[n][m] = S[n * 16 + 8 + m] / (qn * km) * temp[0];
    }
    __syncthreads();
    if (t < 8) {
        float mx = -3.0e38f;
#pragma unroll
        for (int m = 0; m < 8; ++m) mx = fmaxf(mx, sc[t][m]);
        float e[8], ssum = 0.f;
#pragma unroll
        for (int m = 0; m < 8; ++m) { e[m] = expf(sc[t][m] - mx); ssum += e[m]; }
        const float inv = 1.f / ssum;
#pragma unroll
        for (int m = 0; m < 8; ++m) a[t * 8 + m] = e[m] * inv;
    }
    __syncthreads();

    const float* wrow = wproj + (size_t)co * DIM;
    u16* wout = weff + ((size_t)b * DIM + co) * DIM;
    for (int i = t; i < DIM; i += 256) {
        const int m = i / CPG;
        const int c = i - m * CPG;
        float sw = 0.f;
#pragma unroll
        for (int n = 0; n < 8; ++n) sw += wrow[n * CPG + c] * a[n * 8 + m];
        wout[i] = f2bf(sw);
    }
}

extern "C" void kernel_launch(void* const* d_in, const int* in_sizes, int n_in,
                              void* d_out, int out_size, void* d_ws, size_t ws_size,
                              hipStream_t stream)
{
    const float* x      = (const float*)d_in[0];
    const float* temp   = (const float*)d_in[1];
    const float* w_qkv  = (const float*)d_in[2];
    const float* b_qkv  = (const float*)d_in[3];
    const float* w_dw   = (const float*)d_in[4];
    const float* b_dw   = (const float*)d_in[5];
    const float* w_proj = (const float*)d_in[6];
    const float* b_proj = (const float*)d_in[7];
    float* out = (float*)d_out;

    char* ws = (char*)d_ws;
    const size_t SZ_QKV = (size_t)BB * DIM3 * PP * sizeof(u16);  // 150,994,944
    const size_t SZ_XT  = (size_t)BB * PP * DIM * sizeof(u16);   //  50,331,648

    // region 0: [0, SZ_QKV) -- y1 (gemm0 out; read by k_dw2)
    u16* y1 = (u16*)ws;

    // region 1: [SZ_QKV, 2*SZ_QKV)
    u16* xt  = (u16*)(ws + SZ_QKV);               // pre-gemm0 only
    u16* wbf = (u16*)(ws + SZ_QKV + SZ_XT);       // pre-gemm0 only
    // after gemm0 (xt/wbf dead):
    float* partial = (float*)(ws + SZ_QKV);              // 3,145,728 B
    u16*   weffb   = (u16*)(ws + SZ_QKV + 3211264);      // 1,179,648 B
    float* p2      = (float*)(ws + SZ_QKV + 4456448);    // 65,536 B (ends ~4.5MB)
    u16*   vt      = (u16*)(ws + SZ_QKV + 8388608);      // 50.3MB (ends ~58.7MB)

    k_tr_x<<<dim3(PP / 64, DIM / 64, BB), 256, 0, stream>>>(x, xt, w_qkv, wbf);
    k_gemm<0><<<dim3(128 * 9 * BB), 256, 0, stream>>>(
        wbf, 0, xt, b_qkv, y1, nullptr, nullptr, 9);
    k_dw2<<<dim3(1152, BB), 256, 0, stream>>>(y1, w_dw, b_dw, vt, partial);
    k_red<<<dim3(16, BB), 256, 0, stream>>>(partial, p2);
    k_weff<<<dim3(DIM, BB), 256, 0, stream>>>(p2, temp, w_proj, weffb);
    k_gemm<1><<<dim3(128 * 3 * BB), 256, 0, stream>>>(
        weffb, DIM * DIM, vt, b_proj, nullptr, x, out, 3);
}

// Round 20
// 237.356 us; speedup vs baseline: 1.2069x; 1.0460x over previous
//
#include <hip/hip_runtime.h>
#include <hip/hip_bf16.h>

#define BB 4
#define CPG 48
#define HH 128
#define WW2 128
#define PP 16384
#define DIM 384
#define DIM3 1152

typedef unsigned short u16;
typedef __attribute__((ext_vector_type(8))) short bf16x8;
typedef __attribute__((ext_vector_type(4))) float f32x4;

__device__ __forceinline__ float bf2f(u16 u) {
    return __uint_as_float(((unsigned int)u) << 16);
}
__device__ __forceinline__ u16 f2bf(float f) {
    unsigned int u = __float_as_uint(f);
    unsigned int r = (u + 0x7fffu + ((u >> 16) & 1u)) >> 16;
    return (u16)r;
}

// LDS swizzle: rows are 128B; XOR the 16B-slot index with (row&7) to spread banks
__device__ __forceinline__ int swz(int row, int kb) {
    return row * 128 + (kb ^ ((row & 7) << 4));
}

// async global->LDS, 16B per lane; LDS dest = wave-uniform base + lane*16
__device__ __forceinline__ void gld_lds16(const u16* g, char* l) {
    __builtin_amdgcn_global_load_lds(
        (const __attribute__((address_space(1))) void*)g,
        (__attribute__((address_space(3))) void*)l, 16, 0, 0);
}

// ---------------- transpose x [b][k=384][p] fp32 -> Xt [b][p][k=384] bf16
// (+ first 432 flat blocks also convert w_qkv fp32 -> bf16)
__global__ __launch_bounds__(256) void k_tr_x(const float* __restrict__ x,
                                              u16* __restrict__ xt,
                                              const float* __restrict__ w,
                                              u16* __restrict__ wbf)
{
    const int b = blockIdx.z;
    const int k0 = blockIdx.y * 64;
    const int p0 = blockIdx.x * 64;
    const int t = threadIdx.x;
    __shared__ u16 T[64][68];

    // side job: w_qkv convert (432 blocks x 1024 elems = 442,368)
    const int fb = (blockIdx.z * 6 + blockIdx.y) * 256 + blockIdx.x;
    if (fb < 432) {
        const int i4 = (fb * 256 + t) * 4;
        float4 v = *reinterpret_cast<const float4*>(w + i4);
        ushort4 s;
        s.x = f2bf(v.x); s.y = f2bf(v.y); s.z = f2bf(v.z); s.w = f2bf(v.w);
        *reinterpret_cast<ushort4*>(wbf + i4) = s;
    }

    const int kl = t >> 4;          // 0..15
    const int pl = (t & 15) * 4;    // 0..60
#pragma unroll
    for (int ks = 0; ks < 4; ++ks) {
        const int k = ks * 16 + kl;
        float4 v = *reinterpret_cast<const float4*>(&x[((size_t)b * DIM + k0 + k) * PP + p0 + pl]);
        ushort4 s;
        s.x = f2bf(v.x); s.y = f2bf(v.y); s.z = f2bf(v.z); s.w = f2bf(v.w);
        *reinterpret_cast<ushort4*>(&T[k][pl]) = s;
    }
    __syncthreads();
    const int pr = t >> 2;          // 0..63
    const int kg = (t & 3) * 16;    // 0,16,32,48
    __align__(16) u16 tmp[16];
#pragma unroll
    for (int j = 0; j < 16; ++j) tmp[j] = T[kg + j][pr];
    u16* dst = xt + ((size_t)b * PP + p0 + pr) * DIM + k0 + kg;
    *reinterpret_cast<uint4*>(dst)     = *reinterpret_cast<uint4*>(tmp);
    *reinterpret_cast<uint4*>(dst + 8) = *reinterpret_cast<uint4*>(tmp + 8);
}

// ---------------- MFMA GEMM: C[b][co][p] = sum_k A[(b)][co][k] * Bt[b][p][k]
// MODE 0: += bias, write bf16 ybf.  MODE 1: += bias + xres, write fp32 fout.
// Staging via global_load_lds(16B) with pre-swizzled per-lane GLOBAL source.
template<int MODE>
__global__ __launch_bounds__(256) void k_gemm(const u16* __restrict__ A, int aStride,
                                              const u16* __restrict__ Bt,
                                              const float* __restrict__ bias,
                                              u16* __restrict__ ybf,
                                              const float* __restrict__ xres,
                                              float* __restrict__ fout,
                                              int nyTiles)
{
    const int bid = blockIdx.x;
    const int xcd = bid & 7;
    const int r1  = bid >> 3;
    const int px  = xcd * 16 + (r1 & 15);   // p-tile 0..127
    const int r2  = r1 >> 4;
    const int b   = r2 / nyTiles;           // batch
    const int yt  = r2 - b * nyTiles;       // co-tile
    const int co0 = yt * 128;
    const int p0  = px * 128;

    const int t   = threadIdx.x;
    const int l   = t & 63;
    const int wid = t >> 6;
    const int wr  = wid >> 1;      // 0..1 -> row half
    const int wc  = wid & 1;       // 0..1 -> col half
    const int lr  = l & 15;
    const int lg  = l >> 4;        // 0..3

    __shared__ __align__(16) char lds[32768];
    char* AsB = lds;               // [128 rows][64 k] bf16, swizzled content
    char* BsB = lds + 16384;

    f32x4 acc[4][4];
#pragma unroll
    for (int m = 0; m < 4; ++m)
#pragma unroll
        for (int n = 0; n < 4; ++n) acc[m][n] = (f32x4){0.f, 0.f, 0.f, 0.f};

    const u16* Ab  = A  + (size_t)b * aStride;
    const u16* Btb = Bt + (size_t)b * PP * DIM;

    // per-lane source mapping for gld_lds16 (8 rows / wave-issue)
    const int lrow8 = l >> 3;                 // 0..7 within the 8-row group
    const int sl    = l & 7;                  // 16B slot 0..7 within 128B row

    for (int k0 = 0; k0 < DIM; k0 += 64) {
        if (k0) __syncthreads();   // prev iter's LDS reads complete
#pragma unroll
        for (int i = 0; i < 4; ++i) {
            const int rbase = wid * 32 + i * 8;
            const int row   = rbase + lrow8;
            const int elem  = (sl * 8) ^ ((row & 7) << 3);   // inverse swizzle
            gld_lds16(Ab  + (size_t)(co0 + row) * DIM + k0 + elem, AsB + rbase * 128);
            gld_lds16(Btb + (size_t)(p0  + row) * DIM + k0 + elem, BsB + rbase * 128);
        }
        __syncthreads();           // drains vmcnt(0) then barrier -> tiles ready

#pragma unroll
        for (int kk = 0; kk < 64; kk += 32) {
            const int kbyte = kk * 2 + lg * 16;
            bf16x8 av[4], bv[4];
#pragma unroll
            for (int m = 0; m < 4; ++m) {
                const int row = wr * 64 + m * 16 + lr;
                av[m] = *reinterpret_cast<const bf16x8*>(AsB + swz(row, kbyte));
            }
#pragma unroll
            for (int n = 0; n < 4; ++n) {
                const int row = wc * 64 + n * 16 + lr;
                bv[n] = *reinterpret_cast<const bf16x8*>(BsB + swz(row, kbyte));
            }
#pragma unroll
            for (int m = 0; m < 4; ++m)
#pragma unroll
                for (int n = 0; n < 4; ++n)
                    acc[m][n] = __builtin_amdgcn_mfma_f32_16x16x32_bf16(
                        av[m], bv[n], acc[m][n], 0, 0, 0);
        }
    }

    // bias per (m, r): row = wr*64 + m*16 + lg*4 + r
    float bias_r[4][4];
#pragma unroll
    for (int m = 0; m < 4; ++m)
#pragma unroll
        for (int r = 0; r < 4; ++r)
            bias_r[m][r] = bias[co0 + wr * 64 + m * 16 + lg * 4 + r];

    if (MODE == 0) {
        __syncthreads();
        u16* Cs = reinterpret_cast<u16*>(lds);
#pragma unroll
        for (int m = 0; m < 4; ++m)
#pragma unroll
            for (int n = 0; n < 4; ++n)
#pragma unroll
                for (int r = 0; r < 4; ++r) {
                    const int row = wr * 64 + m * 16 + lg * 4 + r;
                    const int col = wc * 64 + n * 16 + lr;
                    Cs[row * 128 + col] = f2bf(acc[m][n][r] + bias_r[m][r]);
                }
        __syncthreads();
        // coalesced store: 16 lanes cover one 256B row segment
        const int rr = t >> 4;          // 0..15
        const int cs = (t & 15) * 8;    // u16 col
#pragma unroll
        for (int j = 0; j < 8; ++j) {
            const int row = j * 16 + rr;
            *reinterpret_cast<uint4*>(&ybf[((size_t)b * DIM3 + co0 + row) * PP + p0 + cs]) =
                *reinterpret_cast<const uint4*>(&Cs[row * 128 + cs]);
        }
    } else {
        // fp32 epilogue via LDS in two 64-row half-passes
        float* Cf = reinterpret_cast<float*>(lds);
#pragma unroll
        for (int h = 0; h < 2; ++h) {
            __syncthreads();
            if (wr == h) {
#pragma unroll
                for (int m = 0; m < 4; ++m)
#pragma unroll
                    for (int n = 0; n < 4; ++n)
#pragma unroll
                        for (int r = 0; r < 4; ++r) {
                            const int lrow = m * 16 + lg * 4 + r;
                            const int col = wc * 64 + n * 16 + lr;
                            Cf[lrow * 128 + col] = acc[m][n][r] + bias_r[m][r];
                        }
            }
            __syncthreads();
            const int rr = t >> 5;          // 0..7
            const int cc = (t & 31) * 4;    // fp32 col
#pragma unroll
            for (int j = 0; j < 8; ++j) {
                const int lrow = j * 8 + rr;
                const int grow = h * 64 + lrow;
                const size_t idx = ((size_t)b * DIM + co0 + grow) * PP + p0 + cc;
                float4 xr = *reinterpret_cast<const float4*>(&xres[idx]);
                float4 cv = *reinterpret_cast<const float4*>(&Cf[lrow * 128 + cc]);
                cv.x += xr.x; cv.y += xr.y; cv.z += xr.z; cv.w += xr.w;
                *reinterpret_cast<float4*>(&fout[idx]) = cv;
            }
        }
    }
}

// halo loads
#define LOADROW3(arr, gr_)                                                     \
    {                                                                          \
        const int r_ = (gr_);                                                  \
        if (r_ >= 0 && r_ < HH) {                                              \
            union { uint4 v; u16 u[8]; } a0_, a1_;                             \
            a0_.v = *reinterpret_cast<const uint4*>(img + r_ * WW2 + c0);      \
            a1_.v = *reinterpret_cast<const uint4*>(img + r_ * WW2 + c0 + 8);  \
            arr[1] = bf2f(a0_.u[0]); arr[2] = bf2f(a0_.u[1]);                  \
            arr[3] = bf2f(a0_.u[2]); arr[4] = bf2f(a0_.u[3]);                  \
            arr[5] = bf2f(a0_.u[4]); arr[6] = bf2f(a0_.u[5]);                  \
            arr[7] = bf2f(a0_.u[6]); arr[8] = bf2f(a0_.u[7]);                  \
            arr[9]  = bf2f(a1_.u[0]); arr[10] = bf2f(a1_.u[1]);                \
            arr[11] = bf2f(a1_.u[2]); arr[12] = bf2f(a1_.u[3]);                \
            arr[13] = bf2f(a1_.u[4]); arr[14] = bf2f(a1_.u[5]);                \
            arr[15] = bf2f(a1_.u[6]); arr[16] = bf2f(a1_.u[7]);                \
        } else {                                                               \
            for (int z_ = 1; z_ <= 16; ++z_) arr[z_] = 0.f;                    \
        }                                                                      \
        float lf_ = __shfl(arr[16], t - 1);                                    \
        float rt_ = __shfl(arr[1],  t + 1);                                    \
        arr[0]  = (s > 0) ? lf_ : 0.f;                                         \
        arr[17] = (s < 7) ? rt_ : 0.f;                                         \
    }

#define LOADROW2(arr, gr_)                                                     \
    {                                                                          \
        const int r_ = (gr_);                                                  \
        if (r_ >= 0 && r_ < HH) {                                              \
            union { uint4 v; u16 u[8]; } cc_;                                  \
            cc_.v = *reinterpret_cast<const uint4*>(img + r_ * WW2 + sp);      \
            arr[1] = bf2f(cc_.u[0]); arr[2] = bf2f(cc_.u[1]);                  \
            arr[3] = bf2f(cc_.u[2]); arr[4] = bf2f(cc_.u[3]);                  \
            arr[5] = bf2f(cc_.u[4]); arr[6] = bf2f(cc_.u[5]);                  \
            arr[7] = bf2f(cc_.u[6]); arr[8] = bf2f(cc_.u[7]);                  \
        } else {                                                               \
            arr[1] = 0.f; arr[2] = 0.f; arr[3] = 0.f; arr[4] = 0.f;            \
            arr[5] = 0.f; arr[6] = 0.f; arr[7] = 0.f; arr[8] = 0.f;            \
        }                                                                      \
        float lf_ = __shfl(arr[8], t - 1);                                     \
        float rt_ = __shfl(arr[1], t + 1);                                     \
        arr[0] = (s > 0)  ? lf_ : 0.f;                                         \
        arr[9] = (s < 15) ? rt_ : 0.f;                                         \
    }

// ---------------- merged dw kernel: id<384 -> dw(v)+transpose; else dw(q,k)+Gram
// LDS exactly 32768 B (XOR swizzles, red aliased) -> 5 blocks/CU.
__global__ __launch_bounds__(256) void k_dw2(const u16* __restrict__ y1,
                                             const float* __restrict__ wdw,
                                             const float* __restrict__ bdw,
                                             u16* __restrict__ vt,
                                             float* __restrict__ partial)
{
    __shared__ __align__(16) char lds[32768];
    const int id = blockIdx.x;     // 0..1151
    const int b  = blockIdx.y;
    const int t  = (int)threadIdx.x;

    if (id < 384) {
        // ---- dw(v) + transpose ----  T logical [32][512], XOR bank swizzle
        const int band = id & 31;      // 4-row band
        const int chg  = id >> 5;      // 32-ch group 0..11
        const int ch   = t >> 3;       // 0..31
        const int s    = t & 7;        // 16-px strip
        const int c0   = s * 16;
        const int r0   = band * 4;

        const int gch = 2 * DIM + chg * 32 + ch;
        const u16* img = y1 + ((size_t)b * DIM3 + gch) * PP;

        float w9[9];
#pragma unroll
        for (int i = 0; i < 9; ++i) w9[i] = wdw[gch * 9 + i];
        const float bv = bdw[gch];

        const int chx = (ch & 7) << 4;         // XOR on byte bits 4..6

        float A[18], B[18], C[18];
        LOADROW3(A, r0 - 1);
        LOADROW3(B, r0);

#pragma unroll
        for (int j = 0; j < 4; ++j) {
            LOADROW3(C, r0 + j + 1);
            union { uint4 v[2]; u16 u[16]; } og;
#pragma unroll
            for (int cidx = 0; cidx < 16; ++cidx) {
                float a = bv;
                a = fmaf(w9[0], A[cidx],     a);
                a = fmaf(w9[1], A[cidx + 1], a);
                a = fmaf(w9[2], A[cidx + 2], a);
                a = fmaf(w9[3], B[cidx],     a);
                a = fmaf(w9[4], B[cidx + 1], a);
                a = fmaf(w9[5], B[cidx + 2], a);
                a = fmaf(w9[6], C[cidx],     a);
                a = fmaf(w9[7], C[cidx + 1], a);
                a = fmaf(w9[8], C[cidx + 2], a);
                og.u[cidx] = f2bf(a);
            }
            const int base = ch * 1024 + j * 256 + s * 32;
            *reinterpret_cast<uint4*>(lds + ((base)      ^ chx)) = og.v[0];
            *reinterpret_cast<uint4*>(lds + ((base + 16) ^ chx)) = og.v[1];
#pragma unroll
            for (int q = 0; q < 18; ++q) { A[q] = B[q]; B[q] = C[q]; }
        }
        __syncthreads();

        // transpose store: lane = px, gather 32 ch, 64B/px line
#pragma unroll
        for (int j = 0; j < 2; ++j) {
            const int px = j * 256 + t;           // 0..511
            union { uint4 v[4]; u16 u[32]; } ov;
#pragma unroll
            for (int c2 = 0; c2 < 32; ++c2)
                ov.u[c2] = *reinterpret_cast<const u16*>(
                    lds + ((c2 * 1024 + px * 2) ^ ((c2 & 7) << 4)));
            u16* dst = vt + ((size_t)b * PP + band * 512 + px) * DIM + chg * 32;
            *reinterpret_cast<uint4*>(dst)      = ov.v[0];
            *reinterpret_cast<uint4*>(dst + 8)  = ov.v[1];
            *reinterpret_cast<uint4*>(dst + 16) = ov.v[2];
            *reinterpret_cast<uint4*>(dst + 24) = ov.v[3];
        }
    } else {
        // ---- dw(q,k) + MFMA self-Gram ----  G logical [16][1024], XOR swizzle
        const int id2  = id - 384;
        const int c    = id2 % 48;
        const int band = id2 / 48;     // 0..15
        const int h    = t >> 7;
        const int r    = (t >> 4) & 7;
        const int s    = t & 15;
        const int sp   = s * 8;
        const int r0   = band * 8;

#pragma unroll
        for (int n = 0; n < 8; ++n) {
            const int gch = h * DIM + n * CPG + c;
            const u16* img = y1 + ((size_t)b * DIM3 + gch) * PP;
            float w9[9];
#pragma unroll
            for (int i = 0; i < 9; ++i) w9[i] = wdw[gch * 9 + i];
            const float bv = bdw[gch];

            float A[10], B[10], C[10];
            LOADROW2(A, r0 + r - 1);
            LOADROW2(B, r0 + r);
            LOADROW2(C, r0 + r + 1);

            union { uint4 v; u16 u[8]; } og;
#pragma unroll
            for (int j = 0; j < 8; ++j) {
                float a = bv;
                a = fmaf(w9[0], A[j],     a);
                a = fmaf(w9[1], A[j + 1], a);
                a = fmaf(w9[2], A[j + 2], a);
                a = fmaf(w9[3], B[j],     a);
                a = fmaf(w9[4], B[j + 1], a);
                a = fmaf(w9[5], B[j + 2], a);
                a = fmaf(w9[6], C[j],     a);
                a = fmaf(w9[7], C[j + 1], a);
                a = fmaf(w9[8], C[j + 2], a);
                og.u[j] = f2bf(a);
            }
            const int grow = h * 8 + n;
            const int gb = (grow * 2048 + r * 256 + s * 16) ^ ((grow & 7) << 4);
            *reinterpret_cast<uint4*>(lds + gb) = og.v;
        }
        __syncthreads();

        // Gram: wave w covers K range [w*256, w*256+256)
        const int l = t & 63, w = t >> 6;
        const int grow = l & 15;
        const int koc  = (l >> 4) * 8;
        f32x4 acc = (f32x4){0.f, 0.f, 0.f, 0.f};
#pragma unroll
        for (int q8 = 0; q8 < 8; ++q8) {
            const int kb = (grow * 2048 + (w * 256 + q8 * 32 + koc) * 2)
                           ^ ((grow & 7) << 4);
            bf16x8 g = *reinterpret_cast<const bf16x8*>(lds + kb);
            acc = __builtin_amdgcn_mfma_f32_16x16x32_bf16(g, g, acc, 0, 0, 0);
        }
        __syncthreads();   // all gram reads done before red aliases G

        float* red = reinterpret_cast<float*>(lds);
        // C/D layout: col = lane&15, row = (lane>>4)*4 + reg  ->  S[row][col]
#pragma unroll
        for (int rg = 0; rg < 4; ++rg)
            red[w * 256 + ((l >> 4) * 4 + rg) * 16 + (l & 15)] = acc[rg];
        __syncthreads();

        const float sum = red[t] + red[256 + t] + red[512 + t] + red[768 + t];
        partial[((size_t)((b * 48 + c) * 16 + band)) * 256 + t] = sum;
    }
}

// ---------------- stage-A reduce: 768 partial rows -> 16 rows per batch
__global__ __launch_bounds__(256) void k_red(const float* __restrict__ partial,
                                             float* __restrict__ p2)
{
    const int g = blockIdx.x;      // 0..15
    const int b = blockIdx.y;
    const int t = threadIdx.x;
    const float* base = partial + ((size_t)b * 768 + g * 48) * 256 + t;
    float s = 0.f;
#pragma unroll 4
    for (int i = 0; i < 48; ++i) s += base[(size_t)i * 256];
    p2[((size_t)b * 16 + g) * 256 + t] = s;
}

// ---------------- Weff (with in-block attn reconstruction from p2)
__global__ __launch_bounds__(256) void k_weff(const float* __restrict__ p2,
                                              const float* __restrict__ temp,
                                              const float* __restrict__ wproj,
                                              u16* __restrict__ weff)
{
    const int b  = blockIdx.y;
    const int co = blockIdx.x;
    const int t  = threadIdx.x;
    __shared__ float S[256];
    __shared__ float sc[8][8];
    __shared__ float a[64];

    float s = 0.f;
#pragma unroll
    for (int i = 0; i < 16; ++i)
        s += p2[((size_t)b * 16 + i) * 256 + t];
    S[t] = s;
    __syncthreads();
    if (t < 64) {
        const int n = t >> 3, m = t & 7;
        const float qn = fmaxf(sqrtf(S[n * 16 + n]), 1e-12f);
        const float km = fmaxf(sqrtf(S[(8 + m) * 16 + 8 + m]), 1e-12f);
        sc[n][m] = S[n * 16 + 8 + m] / (qn * km) * temp[0];
    }
    __syncthreads();
    if (t < 8) {
        float mx = -3.0e38f;
#pragma unroll
        for (int m = 0; m < 8; ++m) mx = fmaxf(mx, sc[t][m]);
        float e[8], ssum = 0.f;
#pragma unroll
        for (int m = 0; m < 8; ++m) { e[m] = expf(sc[t][m] - mx); ssum += e[m]; }
        const float inv = 1.f / ssum;
#pragma unroll
        for (int m = 0; m < 8; ++m) a[t * 8 + m] = e[m] * inv;
    }
    __syncthreads();

    const float* wrow = wproj + (size_t)co * DIM;
    u16* wout = weff + ((size_t)b * DIM + co) * DIM;
    for (int i = t; i < DIM; i += 256) {
        const int m = i / CPG;
        const int c = i - m * CPG;
        float sw = 0.f;
#pragma unroll
        for (int n = 0; n < 8; ++n) sw += wrow[n * CPG + c] * a[n * 8 + m];
        wout[i] = f2bf(sw);
    }
}

extern "C" void kernel_launch(void* const* d_in, const int* in_sizes, int n_in,
                              void* d_out, int out_size, void* d_ws, size_t ws_size,
                              hipStream_t stream)
{
    const float* x      = (const float*)d_in[0];
    const float* temp   = (const float*)d_in[1];
    const float* w_qkv  = (const float*)d_in[2];
    const float* b_qkv  = (const float*)d_in[3];
    const float* w_dw   = (const float*)d_in[4];
    const float* b_dw   = (const float*)d_in[5];
    const float* w_proj = (const float*)d_in[6];
    const float* b_proj = (const float*)d_in[7];
    float* out = (float*)d_out;

    char* ws = (char*)d_ws;
    const size_t SZ_QKV = (size_t)BB * DIM3 * PP * sizeof(u16);  // 150,994,944
    const size_t SZ_XT  = (size_t)BB * PP * DIM * sizeof(u16);   //  50,331,648

    // region 0: [0, SZ_QKV) -- y1 (gemm0 out; read by k_dw2)
    u16* y1 = (u16*)ws;

    // region 1: [SZ_QKV, 2*SZ_QKV)
    u16* xt  = (u16*)(ws + SZ_QKV);               // pre-gemm0 only
    u16* wbf = (u16*)(ws + SZ_QKV + SZ_XT);       // pre-gemm0 only
    // after gemm0 (xt/wbf dead):
    float* partial = (float*)(ws + SZ_QKV);              // 3,145,728 B
    u16*   weffb   = (u16*)(ws + SZ_QKV + 3211264);      // 1,179,648 B
    float* p2      = (float*)(ws + SZ_QKV + 4456448);    // 65,536 B (ends ~4.5MB)
    u16*   vt      = (u16*)(ws + SZ_QKV + 8388608);      // 50.3MB (ends ~58.7MB)

    k_tr_x<<<dim3(PP / 64, DIM / 64, BB), 256, 0, stream>>>(x, xt, w_qkv, wbf);
    k_gemm<0><<<dim3(128 * 9 * BB), 256, 0, stream>>>(
        wbf, 0, xt, b_qkv, y1, nullptr, nullptr, 9);
    k_dw2<<<dim3(1152, BB), 256, 0, stream>>>(y1, w_dw, b_dw, vt, partial);
    k_red<<<dim3(16, BB), 256, 0, stream>>>(partial, p2);
    k_weff<<<dim3(DIM, BB), 256, 0, stream>>>(p2, temp, w_proj, weffb);
    k_gemm<1><<<dim3(128 * 3 * BB), 256, 0, stream>>>(
        weffb, DIM * DIM, vt, b_proj, nullptr, x, out, 3);
}